// Round 12
// baseline (648.937 us; speedup 1.0000x reference)
//
#include <hip/hip_runtime.h>
#include <hip/hip_bf16.h>

#define IN_DIM 1024
#define HID 512
#define OUTD 256

typedef __attribute__((ext_vector_type(8))) short short8;
typedef __attribute__((ext_vector_type(4))) float f32x4;
typedef __attribute__((ext_vector_type(8))) unsigned short ushort8e;
typedef __attribute__((ext_vector_type(4))) unsigned short ushort4e;
typedef __attribute__((ext_vector_type(4))) unsigned int uint4e;

template<int F> struct VecSel;
template<> struct VecSel<8> { using T = ushort8e; };
template<> struct VecSel<4> { using T = ushort4e; };

// ---------------- helpers ----------------

__device__ inline unsigned short f2bf(float f) {
    union { float f; unsigned u; } v; v.f = f;
    unsigned r = (v.u + 0x7FFF + ((v.u >> 16) & 1)) >> 16;  // RNE
    return (unsigned short)r;
}

__device__ inline float bf2f(unsigned short u) {
    union { unsigned u; float f; } v; v.u = ((unsigned)u) << 16; return v.f;
}

// pack two f32 -> two bf16 (round-to-nearest, ties up): one add each + byte-perm
__device__ inline unsigned pk2(float a, float b) {
    unsigned ua = __float_as_uint(a) + 0x8000u;
    unsigned ub = __float_as_uint(b) + 0x8000u;
#if __has_builtin(__builtin_amdgcn_perm)
    return __builtin_amdgcn_perm(ub, ua, 0x07060302u);   // D = ua[31:16] | ub[31:16]<<16
#else
    return (ua >> 16) | (ub & 0xFFFF0000u);
#endif
}

// ---------------- degree / norm ----------------

__global__ void deg_kernel(const int* __restrict__ src, const int* __restrict__ dst,
                           int* __restrict__ dego, int* __restrict__ degi, int E) {
    int i = blockIdx.x * blockDim.x + threadIdx.x;
    if (i < E) {
        atomicAdd(&dego[src[i]], 1);
        atomicAdd(&degi[dst[i]], 1);
    }
}

__global__ void invsqrt_kernel(const int* __restrict__ dego, const int* __restrict__ degi,
                               float* __restrict__ iso, float* __restrict__ isi, int n) {
    int i = blockIdx.x * blockDim.x + threadIdx.x;
    if (i < n) {
        iso[i] = rsqrtf(fmaxf((float)dego[i], 1.0f));
        isi[i] = rsqrtf(fmaxf((float)degi[i], 1.0f));
    }
}

// ---------------- exclusive scan over N=65536 (256 blocks x 256) ----------------

__global__ __launch_bounds__(256) void scan_block(const int* __restrict__ deg,
                                                  int* __restrict__ excl,
                                                  int* __restrict__ partials) {
    __shared__ int tmp[256];
    int tid = threadIdx.x;
    int i = blockIdx.x * 256 + tid;
    int v = deg[i];
    tmp[tid] = v;
    __syncthreads();
    #pragma unroll
    for (int off = 1; off < 256; off <<= 1) {
        int t = (tid >= off) ? tmp[tid - off] : 0;
        __syncthreads();
        tmp[tid] += t;
        __syncthreads();
    }
    excl[i] = tmp[tid] - v;
    if (tid == 255) partials[blockIdx.x] = tmp[255];
}

__global__ __launch_bounds__(256) void scan_partials(int* __restrict__ partials) {
    __shared__ int tmp[256];
    int tid = threadIdx.x;
    int v = partials[tid];
    tmp[tid] = v;
    __syncthreads();
    #pragma unroll
    for (int off = 1; off < 256; off <<= 1) {
        int t = (tid >= off) ? tmp[tid - off] : 0;
        __syncthreads();
        tmp[tid] += t;
        __syncthreads();
    }
    partials[tid] = tmp[tid] - v;   // exclusive
}

__global__ __launch_bounds__(256) void scan_add(const int* __restrict__ excl,
                                                const int* __restrict__ partials,
                                                const int* __restrict__ deg,
                                                int* __restrict__ row_start,
                                                int* __restrict__ cursor, int n) {
    int i = blockIdx.x * 256 + threadIdx.x;
    int v = excl[i] + partials[blockIdx.x];
    row_start[i] = v;
    cursor[i] = v;
    if (i == n - 1) row_start[n] = v + deg[i];
}

__global__ void csr_fill(const int* __restrict__ src, const int* __restrict__ dst,
                         int* __restrict__ cursor, int* __restrict__ eidx, int E) {
    int e = blockIdx.x * blockDim.x + threadIdx.x;
    if (e < E) {
        int pos = atomicAdd(&cursor[dst[e]], 1);
        eidx[pos] = src[e];
    }
}

// ---------------- weight transpose+cvt ----------------

__global__ void transpose_cvt(const float* __restrict__ W, unsigned short* __restrict__ Wt,
                              int K, int N) {
    int i = blockIdx.x * 256 + threadIdx.x;
    if (i < N * K) {
        int n = i / K, k = i - n * K;
        Wt[i] = f2bf(W[(size_t)k * N + n]);
    }
}

// ---------------- LDS-free direct-fragment MFMA GEMM ----------------
// C = A[M,KC] @ Bt[NC,KC]^T, bf16 out. MFMA fragment = lane(l): 8 contiguous
// K-elements at row (l&15), chunk (l>>4)*8 -> loadable straight from global.
// No LDS, no barriers; waves independent; compiler pipelines loads across K.
// x2 intra-block redundancy (wc-pair shares A, wr-pair shares B) hits L1/L2.
// AF32=1: A f32, packed to bf16 via add+v_perm (nearest rounding).

#define TM 128
#define TN 128
#define NXCD 8

template<int AF32, int KC, int NC>
__global__ __launch_bounds__(256) void gemm_direct(
    const void* __restrict__ Ap, const unsigned short* __restrict__ Bt,
    unsigned short* __restrict__ Cb, int M)
{
    const int tid  = threadIdx.x;
    const int lane = tid & 63;
    const int wave = tid >> 6;
    const int wr = wave >> 1, wc = wave & 1;
    const int lrow = lane & 15;
    const int lkg  = lane >> 4;

    // XCD swizzle: siblings sharing an A-panel run on the same XCD
    const int nwg = gridDim.x;                // divisible by 8
    const int per = nwg / NXCD;
    const int lin = blockIdx.x;
    const int newlin = (lin % NXCD) * per + lin / NXCD;
    const int ncb = NC / TN;
    const int m0 = (newlin / ncb) * TM;
    const int n0 = (newlin % ncb) * TN;

    const float* Af = (const float*)Ap;
    const unsigned short* Ab = (const unsigned short*)Ap;

    const float* pAf[4];
    const unsigned short* pAb[4];
    const unsigned short* pB[4];
    #pragma unroll
    for (int mi = 0; mi < 4; ++mi) {
        const int row = m0 + wr * 64 + mi * 16 + lrow;
        if (AF32) pAf[mi] = Af + (size_t)row * KC + lkg * 8;
        else      pAb[mi] = Ab + (size_t)row * KC + lkg * 8;
    }
    #pragma unroll
    for (int ni = 0; ni < 4; ++ni) {
        const int col = n0 + wc * 64 + ni * 16 + lrow;
        pB[ni] = Bt + (size_t)col * KC + lkg * 8;
    }

    f32x4 acc[4][4] = {};

    #pragma unroll 4
    for (int kt = 0; kt < KC / 32; ++kt) {
        short8 af[4], bfr[4];
        #pragma unroll
        for (int mi = 0; mi < 4; ++mi) {
            if (AF32) {
                float4 x = *reinterpret_cast<const float4*>(pAf[mi] + kt * 32);
                float4 y = *reinterpret_cast<const float4*>(pAf[mi] + kt * 32 + 4);
                uint4e u;
                u[0] = pk2(x.x, x.y); u[1] = pk2(x.z, x.w);
                u[2] = pk2(y.x, y.y); u[3] = pk2(y.z, y.w);
                af[mi] = *reinterpret_cast<short8*>(&u);
            } else {
                af[mi] = *reinterpret_cast<const short8*>(pAb[mi] + kt * 32);
            }
        }
        #pragma unroll
        for (int ni = 0; ni < 4; ++ni)
            bfr[ni] = *reinterpret_cast<const short8*>(pB[ni] + kt * 32);

        #pragma unroll
        for (int mi = 0; mi < 4; ++mi)
            #pragma unroll
            for (int ni = 0; ni < 4; ++ni)
                acc[mi][ni] = __builtin_amdgcn_mfma_f32_16x16x32_bf16(
                    af[mi], bfr[ni], acc[mi][ni], 0, 0, 0);
    }

    #pragma unroll
    for (int mi = 0; mi < 4; ++mi)
        #pragma unroll
        for (int ni = 0; ni < 4; ++ni)
            #pragma unroll
            for (int r = 0; r < 4; ++r)
                Cb[(size_t)(m0 + wr * 64 + mi * 16 + lkg * 4 + r) * NC
                   + (n0 + wc * 64 + ni * 16 + lrow)] = f2bf(acc[mi][ni][r]);
}

// ---------------- CSR gather-aggregate (bf16 X), fused epilogues ----------------
// One wave per node; lane owns DIM/64 contiguous elems; 4-edge unroll.
// LAYER1: acc = sum iso[src]*X[src]; out_bf = bf16(elu(acc*isi + b1) * iso[node])
// else:   acc = sum X[src];          out_f  = acc*isi + b2

template<int DIM, bool LAYER1>
__global__ __launch_bounds__(256) void aggregate(
    const int* __restrict__ row_start, const int* __restrict__ eidx,
    const unsigned short* __restrict__ Xb, const float* __restrict__ isi,
    const float* __restrict__ iso, const float* __restrict__ bias,
    unsigned short* __restrict__ out_bf, float* __restrict__ out_f)
{
    constexpr int F = DIM / 64;           // 8 (HID) or 4 (OUTD)
    using VecT = typename VecSel<F>::T;
    const int node = blockIdx.x * 4 + (threadIdx.x >> 6);
    const int lane = threadIdx.x & 63;

    const int beg = row_start[node];
    const int end = row_start[node + 1];
    const unsigned short* base = Xb + lane * F;

    float acc[F] = {};
    int e = beg;
    for (; e + 3 < end; e += 4) {
        int i0 = eidx[e], i1 = eidx[e + 1], i2 = eidx[e + 2], i3 = eidx[e + 3];
        float s0 = 1.f, s1 = 1.f, s2 = 1.f, s3 = 1.f;
        if (LAYER1) { s0 = iso[i0]; s1 = iso[i1]; s2 = iso[i2]; s3 = iso[i3]; }
        VecT v0 = *reinterpret_cast<const VecT*>(base + (size_t)i0 * DIM);
        VecT v1 = *reinterpret_cast<const VecT*>(base + (size_t)i1 * DIM);
        VecT v2 = *reinterpret_cast<const VecT*>(base + (size_t)i2 * DIM);
        VecT v3 = *reinterpret_cast<const VecT*>(base + (size_t)i3 * DIM);
        #pragma unroll
        for (int f = 0; f < F; ++f) {
            if (LAYER1) {
                acc[f] = fmaf(s0, bf2f(v0[f]), acc[f]);
                acc[f] = fmaf(s1, bf2f(v1[f]), acc[f]);
                acc[f] = fmaf(s2, bf2f(v2[f]), acc[f]);
                acc[f] = fmaf(s3, bf2f(v3[f]), acc[f]);
            } else {
                acc[f] += bf2f(v0[f]); acc[f] += bf2f(v1[f]);
                acc[f] += bf2f(v2[f]); acc[f] += bf2f(v3[f]);
            }
        }
    }
    for (; e < end; ++e) {
        int i0 = eidx[e];
        float s0 = LAYER1 ? iso[i0] : 1.f;
        VecT v0 = *reinterpret_cast<const VecT*>(base + (size_t)i0 * DIM);
        #pragma unroll
        for (int f = 0; f < F; ++f)
            acc[f] = LAYER1 ? fmaf(s0, bf2f(v0[f]), acc[f]) : acc[f] + bf2f(v0[f]);
    }

    const float si = isi[node];
    float bv[F];
    #pragma unroll
    for (int q = 0; q < F / 4; ++q)
        *reinterpret_cast<float4*>(&bv[q * 4]) =
            *reinterpret_cast<const float4*>(bias + lane * F + q * 4);

    if (LAYER1) {
        const float so = iso[node];
        short8 o;
        #pragma unroll
        for (int f = 0; f < F; ++f) {
            float v = acc[f] * si + bv[f];
            v = v > 0.f ? v : expm1f(v);
            o[f] = (short)f2bf(v * so);
        }
        *reinterpret_cast<short8*>(out_bf + (size_t)node * DIM + lane * F) = o;
    } else {
        #pragma unroll
        for (int q = 0; q < F / 4; ++q) {
            float4 v = make_float4(acc[q * 4 + 0] * si + bv[q * 4 + 0],
                                   acc[q * 4 + 1] * si + bv[q * 4 + 1],
                                   acc[q * 4 + 2] * si + bv[q * 4 + 2],
                                   acc[q * 4 + 3] * si + bv[q * 4 + 3]);
            *reinterpret_cast<float4*>(out_f + (size_t)node * DIM + lane * F + q * 4) = v;
        }
    }
}

// ---------------- launch ----------------

extern "C" void kernel_launch(void* const* d_in, const int* in_sizes, int n_in,
                              void* d_out, int out_size, void* d_ws, size_t ws_size,
                              hipStream_t stream) {
    const float* h  = (const float*)d_in[0];
    const float* W1 = (const float*)d_in[1];
    const float* b1 = (const float*)d_in[2];
    const float* W2 = (const float*)d_in[3];
    const float* b2 = (const float*)d_in[4];
    const int*   src = (const int*)d_in[5];
    const int*   dst = (const int*)d_in[6];

    const int N = in_sizes[0] / IN_DIM;   // 65536
    const int E = in_sizes[5];            // 524288
    float* out = (float*)d_out;

    // ---- workspace layout ----
    int* dego      = (int*)d_ws;                   // N
    int* degi      = dego + N;                     // N
    int* excl      = degi + N;                     // N
    int* partials  = excl + N;                     // 256
    int* row_start = partials + 256;               // N+1 (pad to N+64)
    int* cursor    = row_start + N + 64;           // N
    int* eidx      = cursor + N;                   // E
    float* iso     = (float*)(eidx + E);           // N
    float* isi     = iso + N;                      // N
    unsigned short* W1t = (unsigned short*)(isi + N);      // IN_DIM*HID
    unsigned short* W2t = W1t + (size_t)IN_DIM * HID;      // HID*OUTD
    unsigned short* X1b = W2t + (size_t)HID * OUTD;        // N*HID bf16 (67MB)
    unsigned short* X2b = X1b;                             // alias (X1 dead before gemm2 write)
    unsigned short* R2h = X1b + (size_t)N * HID;           // N*HID bf16 (67MB) — x1s

    hipMemsetAsync(dego, 0, sizeof(int) * (size_t)2 * N, stream);

    deg_kernel<<<(E + 255) / 256, 256, 0, stream>>>(src, dst, dego, degi, E);
    invsqrt_kernel<<<(N + 255) / 256, 256, 0, stream>>>(dego, degi, iso, isi, N);

    // CSR by dst
    scan_block<<<N / 256, 256, 0, stream>>>(degi, excl, partials);
    scan_partials<<<1, 256, 0, stream>>>(partials);
    scan_add<<<N / 256, 256, 0, stream>>>(excl, partials, degi, row_start, cursor, N);
    csr_fill<<<(E + 255) / 256, 256, 0, stream>>>(src, dst, cursor, eidx, E);

    // weights -> bf16 transposed
    transpose_cvt<<<(IN_DIM * HID + 255) / 256, 256, 0, stream>>>(W1, W1t, IN_DIM, HID);
    transpose_cvt<<<(HID * OUTD + 255) / 256, 256, 0, stream>>>(W2, W2t, HID, OUTD);

    // Layer 1: X1b = bf16(h @ W1) [direct-fragment, cvt in-flight];
    //          agg applies iso[src] during gather
    gemm_direct<1, IN_DIM, HID><<<(N / TM) * (HID / TN), 256, 0, stream>>>(
        h, W1t, X1b, N);
    aggregate<HID, true><<<N / 4, 256, 0, stream>>>(
        row_start, eidx, X1b, isi, iso, b1, R2h, nullptr);

    // Layer 2: X2b = bf16(R2h @ W2) ; out = agg(X2b)*isi + b2
    gemm_direct<0, HID, OUTD><<<(N / TM) * (OUTD / TN), 256, 0, stream>>>(
        R2h, W2t, X2b, N);
    aggregate<OUTD, false><<<N / 4, 256, 0, stream>>>(
        row_start, eidx, X2b, isi, iso, b2, nullptr, out);
}

// Round 13
// 462.921 us; speedup vs baseline: 1.4018x; 1.4018x over previous
//
#include <hip/hip_runtime.h>
#include <hip/hip_bf16.h>

#define IN_DIM 1024
#define HID 512
#define OUTD 256

typedef __attribute__((ext_vector_type(8))) short short8;
typedef __attribute__((ext_vector_type(4))) float f32x4;
typedef __attribute__((ext_vector_type(8))) unsigned short ushort8e;
typedef __attribute__((ext_vector_type(4))) unsigned short ushort4e;

template<int F> struct VecSel;
template<> struct VecSel<8> { using T = ushort8e; };
template<> struct VecSel<4> { using T = ushort4e; };

// ---------------- helpers ----------------

__device__ inline unsigned short f2bf(float f) {
    union { float f; unsigned u; } v; v.f = f;
    unsigned r = (v.u + 0x7FFF + ((v.u >> 16) & 1)) >> 16;  // RNE
    return (unsigned short)r;
}

__device__ inline float bf2f(unsigned short u) {
    union { unsigned u; float f; } v; v.u = ((unsigned)u) << 16; return v.f;
}

__device__ inline void gload16(const void* g, void* l) {
    __builtin_amdgcn_global_load_lds(
        (const __attribute__((address_space(1))) void*)g,
        (__attribute__((address_space(3))) void*)l, 16, 0, 0);
}

// ---------------- degree / norm ----------------

__global__ void deg_kernel(const int* __restrict__ src, const int* __restrict__ dst,
                           int* __restrict__ dego, int* __restrict__ degi, int E) {
    int i = blockIdx.x * blockDim.x + threadIdx.x;
    if (i < E) {
        atomicAdd(&dego[src[i]], 1);
        atomicAdd(&degi[dst[i]], 1);
    }
}

__global__ void invsqrt_kernel(const int* __restrict__ dego, const int* __restrict__ degi,
                               float* __restrict__ iso, float* __restrict__ isi, int n) {
    int i = blockIdx.x * blockDim.x + threadIdx.x;
    if (i < n) {
        iso[i] = rsqrtf(fmaxf((float)dego[i], 1.0f));
        isi[i] = rsqrtf(fmaxf((float)degi[i], 1.0f));
    }
}

// ---------------- exclusive scan over N=65536 (256 blocks x 256) ----------------

__global__ __launch_bounds__(256) void scan_block(const int* __restrict__ deg,
                                                  int* __restrict__ excl,
                                                  int* __restrict__ partials) {
    __shared__ int tmp[256];
    int tid = threadIdx.x;
    int i = blockIdx.x * 256 + tid;
    int v = deg[i];
    tmp[tid] = v;
    __syncthreads();
    #pragma unroll
    for (int off = 1; off < 256; off <<= 1) {
        int t = (tid >= off) ? tmp[tid - off] : 0;
        __syncthreads();
        tmp[tid] += t;
        __syncthreads();
    }
    excl[i] = tmp[tid] - v;
    if (tid == 255) partials[blockIdx.x] = tmp[255];
}

__global__ __launch_bounds__(256) void scan_partials(int* __restrict__ partials) {
    __shared__ int tmp[256];
    int tid = threadIdx.x;
    int v = partials[tid];
    tmp[tid] = v;
    __syncthreads();
    #pragma unroll
    for (int off = 1; off < 256; off <<= 1) {
        int t = (tid >= off) ? tmp[tid - off] : 0;
        __syncthreads();
        tmp[tid] += t;
        __syncthreads();
    }
    partials[tid] = tmp[tid] - v;   // exclusive
}

__global__ __launch_bounds__(256) void scan_add(const int* __restrict__ excl,
                                                const int* __restrict__ partials,
                                                const int* __restrict__ deg,
                                                int* __restrict__ row_start,
                                                int* __restrict__ cursor, int n) {
    int i = blockIdx.x * 256 + threadIdx.x;
    int v = excl[i] + partials[blockIdx.x];
    row_start[i] = v;
    cursor[i] = v;
    if (i == n - 1) row_start[n] = v + deg[i];
}

__global__ void csr_fill(const int* __restrict__ src, const int* __restrict__ dst,
                         int* __restrict__ cursor, int* __restrict__ eidx, int E) {
    int e = blockIdx.x * blockDim.x + threadIdx.x;
    if (e < E) {
        int pos = atomicAdd(&cursor[dst[e]], 1);
        eidx[pos] = src[e];
    }
}

// ---------------- weight transpose+cvt ----------------

__global__ void transpose_cvt(const float* __restrict__ W, unsigned short* __restrict__ Wt,
                              int K, int N) {
    int i = blockIdx.x * 256 + threadIdx.x;
    if (i < N * K) {
        int n = i / K, k = i - n * K;
        Wt[i] = f2bf(W[(size_t)k * N + n]);
    }
}

// ---------------- GEMM1: full-width tile, zero A redundancy ----------------
// C[M,HID] = bf16( (iso ⊙ A[M,IN_DIM]) @ Bt[HID,IN_DIM]^T )
// TM=64, TN=512(=HID): each block owns the FULL N -> every f32 A element
// passes the per-CU vector path exactly once (the R12-diagnosed limiter).
// 4 waves = 4 column quarters (128 cols each), acc[4][8].
// B (1MB, L2-resident) staged via global_load_lds; XOR quad swizzle
// q ^ ((row>>1)&3) on both sides (R4/R8-verified involution).

__global__ __launch_bounds__(256) void gemm1_wide(
    const float* __restrict__ A, const unsigned short* __restrict__ Bt,
    const float* __restrict__ rowscale, unsigned short* __restrict__ Cb, int M)
{
    __shared__ unsigned short As[64][32];    // 4 KB
    __shared__ unsigned short Bs[512][32];   // 32 KB

    const int tid  = threadIdx.x;
    const int lane = tid & 63;
    const int wave = tid >> 6;          // column quarter: cols wave*128..+127
    const int lrow = lane & 15;
    const int lkg  = lane >> 4;

    const int m0 = blockIdx.x * 64;

    char* AsB = (char*)&As[0][0];
    char* BsB = (char*)&Bs[0][0];

    // A staging: thread owns row rA (0..63), logical quad g (8 f32 -> 8 bf16)
    const int rA = tid >> 2;
    const int g  = tid & 3;
    const int qpA = g ^ ((rA >> 1) & 3);
    const float sc = rowscale[m0 + rA];

    const int rslot = (lkg ^ ((lrow >> 1) & 3)) * 8;

    f32x4 acc[4][8] = {};

    const int nk = IN_DIM / 32;
    for (int kt = 0; kt < nk; ++kt) {
        const int k0 = kt * 32;

        // B: 8 x global_load_lds (32 KB), slot s -> row s>>2, src quad swizzled
        #pragma unroll
        for (int i = 0; i < 8; ++i) {
            const int s = i * 256 + wave * 64 + lane;
            const int r = s >> 2;
            const int q = (s & 3) ^ ((s >> 3) & 3);
            gload16(Bt + (size_t)r * IN_DIM + k0 + q * 8,
                    BsB + (i * 256 + wave * 64) * 16);
        }

        // A: 8 f32 -> scale -> bf16 -> one ds_write_b128 (8 KB/block-step)
        {
            const float* pa = A + (size_t)(m0 + rA) * IN_DIM + k0 + g * 8;
            float4 x = *reinterpret_cast<const float4*>(pa);
            float4 y = *reinterpret_cast<const float4*>(pa + 4);
            short8 kv;
            kv[0] = (short)f2bf(x.x * sc); kv[1] = (short)f2bf(x.y * sc);
            kv[2] = (short)f2bf(x.z * sc); kv[3] = (short)f2bf(x.w * sc);
            kv[4] = (short)f2bf(y.x * sc); kv[5] = (short)f2bf(y.y * sc);
            kv[6] = (short)f2bf(y.z * sc); kv[7] = (short)f2bf(y.w * sc);
            *reinterpret_cast<short8*>(AsB + rA * 64 + qpA * 16) = kv;
        }

        __syncthreads();

        short8 af[4], bfr[8];
        #pragma unroll
        for (int mi = 0; mi < 4; ++mi)
            af[mi] = *reinterpret_cast<const short8*>(&As[mi * 16 + lrow][rslot]);
        #pragma unroll
        for (int ni = 0; ni < 8; ++ni)
            bfr[ni] = *reinterpret_cast<const short8*>(&Bs[wave * 128 + ni * 16 + lrow][rslot]);

        #pragma unroll
        for (int mi = 0; mi < 4; ++mi)
            #pragma unroll
            for (int ni = 0; ni < 8; ++ni)
                acc[mi][ni] = __builtin_amdgcn_mfma_f32_16x16x32_bf16(
                    af[mi], bfr[ni], acc[mi][ni], 0, 0, 0);

        __syncthreads();
    }

    #pragma unroll
    for (int mi = 0; mi < 4; ++mi)
        #pragma unroll
        for (int ni = 0; ni < 8; ++ni)
            #pragma unroll
            for (int r = 0; r < 4; ++r)
                Cb[(size_t)(m0 + mi * 16 + lkg * 4 + r) * HID
                   + (wave * 128 + ni * 16 + lrow)] = f2bf(acc[mi][ni][r]);
}

// ---------------- GEMM2 (R8 path): bf16 A/B via gload_lds, BK=64 dbuf ----------------

#define TM 128
#define TN 128
#define TK 64
#define NXCD 8

__global__ __launch_bounds__(256) void gemm2_bf16(
    const unsigned short* __restrict__ Ab, const unsigned short* __restrict__ Bt,
    unsigned short* __restrict__ Cb, int M, int K, int Nc)
{
    __shared__ unsigned short As[2][TM][TK];   // 2 x 16 KB
    __shared__ unsigned short Bs[2][TN][TK];   // 2 x 16 KB

    const int tid  = threadIdx.x;
    const int lane = tid & 63;
    const int wave = tid >> 6;
    const int wr = wave >> 1, wc = wave & 1;
    const int lrow = lane & 15;
    const int lkg  = lane >> 4;

    const int nwg = gridDim.x;                // divisible by 8
    const int per = nwg / NXCD;
    const int lin = blockIdx.x;
    const int newlin = (lin % NXCD) * per + lin / NXCD;
    const int ncb = Nc / TN;
    const int m0 = (newlin / ncb) * TM;
    const int n0 = (newlin % ncb) * TN;

    int srow[4], sq[4];
    #pragma unroll
    for (int i = 0; i < 4; ++i) {
        int s = i * 256 + wave * 64 + lane;
        srow[i] = s >> 3;
        sq[i] = (s & 7) ^ ((s >> 3) & 7);
    }

    char* AsB = (char*)&As[0][0][0];
    char* BsB = (char*)&Bs[0][0][0];

    auto stageOp = [&](const unsigned short* G, int rc0, int kt, char* opBase, int buf) {
        const int k0 = kt * TK;
        #pragma unroll
        for (int i = 0; i < 4; ++i)
            gload16(G + (size_t)(rc0 + srow[i]) * K + k0 + sq[i] * 8,
                    opBase + buf * 16384 + (i * 256 + wave * 64) * 16);
    };

    f32x4 acc[4][4] = {};

    stageOp(Bt, n0, 0, BsB, 0);
    stageOp(Ab, m0, 0, AsB, 0);
    __syncthreads();

    const int nk = K / TK;
    for (int kt = 0; kt < nk; ++kt) {
        const int cur = kt & 1, nxt = cur ^ 1;

        if (kt + 1 < nk) {
            stageOp(Bt, n0, kt + 1, BsB, nxt);
            stageOp(Ab, m0, kt + 1, AsB, nxt);
        }

        #pragma unroll
        for (int ks = 0; ks < 2; ++ks) {
            short8 af[4], bfr[4];
            #pragma unroll
            for (int mi = 0; mi < 4; ++mi) {
                const int row = wr * 64 + mi * 16 + lrow;
                const int qp = (ks * 4 + lkg) ^ (lrow & 7);
                af[mi] = *reinterpret_cast<const short8*>(&As[cur][row][qp * 8]);
            }
            #pragma unroll
            for (int ni = 0; ni < 4; ++ni) {
                const int row = wc * 64 + ni * 16 + lrow;
                const int qp = (ks * 4 + lkg) ^ (lrow & 7);
                bfr[ni] = *reinterpret_cast<const short8*>(&Bs[cur][row][qp * 8]);
            }
            #pragma unroll
            for (int mi = 0; mi < 4; ++mi)
                #pragma unroll
                for (int ni = 0; ni < 4; ++ni)
                    acc[mi][ni] = __builtin_amdgcn_mfma_f32_16x16x32_bf16(
                        af[mi], bfr[ni], acc[mi][ni], 0, 0, 0);
        }

        __syncthreads();
    }

    #pragma unroll
    for (int mi = 0; mi < 4; ++mi)
        #pragma unroll
        for (int ni = 0; ni < 4; ++ni)
            #pragma unroll
            for (int r = 0; r < 4; ++r)
                Cb[(size_t)(m0 + wr * 64 + mi * 16 + lkg * 4 + r) * Nc
                   + (n0 + wc * 64 + ni * 16 + lrow)] = f2bf(acc[mi][ni][r]);
}

// ---------------- CSR gather-aggregate (bf16 X), fused epilogues ----------------

template<int DIM, bool LAYER1>
__global__ __launch_bounds__(256) void aggregate(
    const int* __restrict__ row_start, const int* __restrict__ eidx,
    const unsigned short* __restrict__ Xb, const float* __restrict__ isi,
    const float* __restrict__ iso, const float* __restrict__ bias,
    unsigned short* __restrict__ out_bf, float* __restrict__ out_f)
{
    constexpr int F = DIM / 64;           // 8 (HID) or 4 (OUTD)
    using VecT = typename VecSel<F>::T;
    const int node = blockIdx.x * 4 + (threadIdx.x >> 6);
    const int lane = threadIdx.x & 63;

    const int beg = row_start[node];
    const int end = row_start[node + 1];
    const unsigned short* base = Xb + lane * F;

    float acc[F] = {};
    int e = beg;
    for (; e + 3 < end; e += 4) {
        int i0 = eidx[e], i1 = eidx[e + 1], i2 = eidx[e + 2], i3 = eidx[e + 3];
        VecT v0 = *reinterpret_cast<const VecT*>(base + (size_t)i0 * DIM);
        VecT v1 = *reinterpret_cast<const VecT*>(base + (size_t)i1 * DIM);
        VecT v2 = *reinterpret_cast<const VecT*>(base + (size_t)i2 * DIM);
        VecT v3 = *reinterpret_cast<const VecT*>(base + (size_t)i3 * DIM);
        #pragma unroll
        for (int f = 0; f < F; ++f) {
            acc[f] += bf2f(v0[f]); acc[f] += bf2f(v1[f]);
            acc[f] += bf2f(v2[f]); acc[f] += bf2f(v3[f]);
        }
    }
    for (; e < end; ++e) {
        VecT v0 = *reinterpret_cast<const VecT*>(base + (size_t)eidx[e] * DIM);
        #pragma unroll
        for (int f = 0; f < F; ++f) acc[f] += bf2f(v0[f]);
    }

    const float si = isi[node];
    float bv[F];
    #pragma unroll
    for (int q = 0; q < F / 4; ++q)
        *reinterpret_cast<float4*>(&bv[q * 4]) =
            *reinterpret_cast<const float4*>(bias + lane * F + q * 4);

    if (LAYER1) {
        const float so = iso[node];
        short8 o;
        #pragma unroll
        for (int f = 0; f < F; ++f) {
            float v = acc[f] * si + bv[f];
            v = v > 0.f ? v : expm1f(v);
            o[f] = (short)f2bf(v * so);
        }
        *reinterpret_cast<short8*>(out_bf + (size_t)node * DIM + lane * F) = o;
    } else {
        #pragma unroll
        for (int q = 0; q < F / 4; ++q) {
            float4 v = make_float4(acc[q * 4 + 0] * si + bv[q * 4 + 0],
                                   acc[q * 4 + 1] * si + bv[q * 4 + 1],
                                   acc[q * 4 + 2] * si + bv[q * 4 + 2],
                                   acc[q * 4 + 3] * si + bv[q * 4 + 3]);
            *reinterpret_cast<float4*>(out_f + (size_t)node * DIM + lane * F + q * 4) = v;
        }
    }
}

// ---------------- launch ----------------

extern "C" void kernel_launch(void* const* d_in, const int* in_sizes, int n_in,
                              void* d_out, int out_size, void* d_ws, size_t ws_size,
                              hipStream_t stream) {
    const float* h  = (const float*)d_in[0];
    const float* W1 = (const float*)d_in[1];
    const float* b1 = (const float*)d_in[2];
    const float* W2 = (const float*)d_in[3];
    const float* b2 = (const float*)d_in[4];
    const int*   src = (const int*)d_in[5];
    const int*   dst = (const int*)d_in[6];

    const int N = in_sizes[0] / IN_DIM;   // 65536
    const int E = in_sizes[5];            // 524288
    float* out = (float*)d_out;

    // ---- workspace layout ----
    int* dego      = (int*)d_ws;                   // N
    int* degi      = dego + N;                     // N
    int* excl      = degi + N;                     // N
    int* partials  = excl + N;                     // 256
    int* row_start = partials + 256;               // N+1 (pad to N+64)
    int* cursor    = row_start + N + 64;           // N
    int* eidx      = cursor + N;                   // E
    float* iso     = (float*)(eidx + E);           // N
    float* isi     = iso + N;                      // N
    unsigned short* W1t = (unsigned short*)(isi + N);      // IN_DIM*HID
    unsigned short* W2t = W1t + (size_t)IN_DIM * HID;      // HID*OUTD
    unsigned short* X1b = W2t + (size_t)HID * OUTD;        // N*HID bf16 (67MB)
    unsigned short* X2b = X1b;                             // alias (X1 dead before gemm2 write)
    unsigned short* R2h = X1b + (size_t)N * HID;           // N*HID bf16 (67MB) — x1s

    hipMemsetAsync(dego, 0, sizeof(int) * (size_t)2 * N, stream);

    deg_kernel<<<(E + 255) / 256, 256, 0, stream>>>(src, dst, dego, degi, E);
    invsqrt_kernel<<<(N + 255) / 256, 256, 0, stream>>>(dego, degi, iso, isi, N);

    // CSR by dst
    scan_block<<<N / 256, 256, 0, stream>>>(degi, excl, partials);
    scan_partials<<<1, 256, 0, stream>>>(partials);
    scan_add<<<N / 256, 256, 0, stream>>>(excl, partials, degi, row_start, cursor, N);
    csr_fill<<<(E + 255) / 256, 256, 0, stream>>>(src, dst, cursor, eidx, E);

    // weights -> bf16 transposed
    transpose_cvt<<<(IN_DIM * HID + 255) / 256, 256, 0, stream>>>(W1, W1t, IN_DIM, HID);
    transpose_cvt<<<(HID * OUTD + 255) / 256, 256, 0, stream>>>(W2, W2t, HID, OUTD);

    // Layer 1: X1b = bf16((iso⊙h) @ W1)   [full-width tile, A read once]
    gemm1_wide<<<N / 64, 256, 0, stream>>>(h, W1t, iso, X1b, N);
    aggregate<HID, true><<<N / 4, 256, 0, stream>>>(
        row_start, eidx, X1b, isi, iso, b1, R2h, nullptr);

    // Layer 2: X2b = bf16(R2h @ W2) ; out = agg(X2b)*isi + b2
    gemm2_bf16<<<(N / TM) * (OUTD / TN), 256, 0, stream>>>(
        R2h, W2t, X2b, N, HID, OUTD);
    aggregate<OUTD, false><<<N / 4, 256, 0, stream>>>(
        row_start, eidx, X2b, isi, iso, b2, nullptr, out);
}

// Round 14
// 402.358 us; speedup vs baseline: 1.6128x; 1.1505x over previous
//
#include <hip/hip_runtime.h>
#include <hip/hip_bf16.h>

#define IN_DIM 1024
#define HID 512
#define OUTD 256

typedef __attribute__((ext_vector_type(8))) short short8;
typedef __attribute__((ext_vector_type(4))) float f32x4;
typedef __attribute__((ext_vector_type(8))) unsigned short ushort8e;
typedef __attribute__((ext_vector_type(4))) unsigned short ushort4e;
typedef __attribute__((ext_vector_type(4))) unsigned int uint4e;

template<int F> struct VecSel;
template<> struct VecSel<8> { using T = ushort8e; };
template<> struct VecSel<4> { using T = ushort4e; };

// ---------------- helpers ----------------

__device__ inline unsigned short f2bf(float f) {
    union { float f; unsigned u; } v; v.f = f;
    unsigned r = (v.u + 0x7FFF + ((v.u >> 16) & 1)) >> 16;  // RNE
    return (unsigned short)r;
}

__device__ inline float bf2f(unsigned short u) {
    union { unsigned u; float f; } v; v.u = ((unsigned)u) << 16; return v.f;
}

// two f32 -> packed bf16x2: round-half-up (add 0x8000) + byte-perm pack
__device__ inline unsigned pk2(float a, float b) {
    unsigned ua = __float_as_uint(a) + 0x8000u;
    unsigned ub = __float_as_uint(b) + 0x8000u;
#if __has_builtin(__builtin_amdgcn_perm)
    return __builtin_amdgcn_perm(ub, ua, 0x07060302u);   // lo = ua>>16, hi = ub>>16
#else
    return (ua >> 16) | (ub & 0xFFFF0000u);
#endif
}

__device__ inline void gload16(const void* g, void* l) {
    __builtin_amdgcn_global_load_lds(
        (const __attribute__((address_space(1))) void*)g,
        (__attribute__((address_space(3))) void*)l, 16, 0, 0);
}

// ---------------- degree / norm ----------------

__global__ void deg_kernel(const int* __restrict__ src, const int* __restrict__ dst,
                           int* __restrict__ dego, int* __restrict__ degi, int E) {
    int i = blockIdx.x * blockDim.x + threadIdx.x;
    if (i < E) {
        atomicAdd(&dego[src[i]], 1);
        atomicAdd(&degi[dst[i]], 1);
    }
}

__global__ void invsqrt_kernel(const int* __restrict__ dego, const int* __restrict__ degi,
                               float* __restrict__ iso, float* __restrict__ isi, int n) {
    int i = blockIdx.x * blockDim.x + threadIdx.x;
    if (i < n) {
        iso[i] = rsqrtf(fmaxf((float)dego[i], 1.0f));
        isi[i] = rsqrtf(fmaxf((float)degi[i], 1.0f));
    }
}

// ---------------- exclusive scan over N=65536 (256 blocks x 256) ----------------

__global__ __launch_bounds__(256) void scan_block(const int* __restrict__ deg,
                                                  int* __restrict__ excl,
                                                  int* __restrict__ partials) {
    __shared__ int tmp[256];
    int tid = threadIdx.x;
    int i = blockIdx.x * 256 + tid;
    int v = deg[i];
    tmp[tid] = v;
    __syncthreads();
    #pragma unroll
    for (int off = 1; off < 256; off <<= 1) {
        int t = (tid >= off) ? tmp[tid - off] : 0;
        __syncthreads();
        tmp[tid] += t;
        __syncthreads();
    }
    excl[i] = tmp[tid] - v;
    if (tid == 255) partials[blockIdx.x] = tmp[255];
}

__global__ __launch_bounds__(256) void scan_partials(int* __restrict__ partials) {
    __shared__ int tmp[256];
    int tid = threadIdx.x;
    int v = partials[tid];
    tmp[tid] = v;
    __syncthreads();
    #pragma unroll
    for (int off = 1; off < 256; off <<= 1) {
        int t = (tid >= off) ? tmp[tid - off] : 0;
        __syncthreads();
        tmp[tid] += t;
        __syncthreads();
    }
    partials[tid] = tmp[tid] - v;   // exclusive
}

__global__ __launch_bounds__(256) void scan_add(const int* __restrict__ excl,
                                                const int* __restrict__ partials,
                                                const int* __restrict__ deg,
                                                int* __restrict__ row_start,
                                                int* __restrict__ cursor, int n) {
    int i = blockIdx.x * 256 + threadIdx.x;
    int v = excl[i] + partials[blockIdx.x];
    row_start[i] = v;
    cursor[i] = v;
    if (i == n - 1) row_start[n] = v + deg[i];
}

__global__ void csr_fill(const int* __restrict__ src, const int* __restrict__ dst,
                         int* __restrict__ cursor, int* __restrict__ eidx, int E) {
    int e = blockIdx.x * blockDim.x + threadIdx.x;
    if (e < E) {
        int pos = atomicAdd(&cursor[dst[e]], 1);
        eidx[pos] = src[e];
    }
}

// ---------------- weight transpose+cvt ----------------

__global__ void transpose_cvt(const float* __restrict__ W, unsigned short* __restrict__ Wt,
                              int K, int N) {
    int i = blockIdx.x * 256 + threadIdx.x;
    if (i < N * K) {
        int n = i / K, k = i - n * K;
        Wt[i] = f2bf(W[(size_t)k * N + n]);
    }
}

// ---------------- GEMM1: A f32 staged via global_load_lds, cvt at fragment read ----
// C[M,HID] = bf16( A[M,IN_DIM] @ Bt[HID,IN_DIM]^T ); iso-scale applied in aggregate.
// m97-exact loop: BK=32, single-buffer, 2 barriers, DMA staging both operands.
// A tile float[128][32]: 8 quads/row, XOR swizzle physq = q ^ (row&7)
//   (pre-swizzled GLOBAL source, linear LDS dest; read at (2lkg+j)^(row&7)).
// Conversion f32->bf16 (pk2) happens in the MFMA phase: VALU co-issues with
// matrix pipe, off the staging critical path.

#define NXCD 8

__global__ __launch_bounds__(256) void gemm1_f32lds(
    const float* __restrict__ A, const unsigned short* __restrict__ Bt,
    unsigned short* __restrict__ Cb, int M)
{
    constexpr int K  = IN_DIM;   // 1024
    constexpr int NC = HID;      // 512
    __shared__ float          As[128][32];   // 16 KB
    __shared__ unsigned short Bs[128][32];   // 8 KB

    const int tid  = threadIdx.x;
    const int lane = tid & 63;
    const int wave = tid >> 6;
    const int wr = wave >> 1, wc = wave & 1;
    const int lrow = lane & 15;
    const int lkg  = lane >> 4;

    // XCD swizzle (bijective: 2048 % 8 == 0)
    const int per = gridDim.x / NXCD;
    const int newlin = (blockIdx.x % NXCD) * per + blockIdx.x / NXCD;
    const int ncb = NC / 128;                 // 4
    const int m0 = (newlin / ncb) * 128;
    const int n0 = (newlin % ncb) * 128;

    char* AsB = (char*)&As[0][0];
    char* BsB = (char*)&Bs[0][0];

    // A slots: 1024 x 16B; slot s -> row s>>3, phys quad s&7, src quad ^(row&7)
    int arow[4], aq[4];
    #pragma unroll
    for (int i = 0; i < 4; ++i) {
        int s = i * 256 + wave * 64 + lane;
        arow[i] = s >> 3;
        aq[i] = (s & 7) ^ ((s >> 3) & 7);
    }
    // B slots: 512 x 16B; slot s -> row s>>2, phys quad s&3, src quad ^((row>>1)&3)
    int brow[2], bq[2];
    #pragma unroll
    for (int i = 0; i < 2; ++i) {
        int s = i * 256 + wave * 64 + lane;
        brow[i] = s >> 2;
        bq[i] = (s & 3) ^ ((s >> 3) & 3);
    }

    const int rslotB = (lkg ^ ((lrow >> 1) & 3)) * 8;

    f32x4 acc[4][4] = {};

    for (int kt = 0; kt < K / 32; ++kt) {
        const int k0 = kt * 32;

        #pragma unroll
        for (int i = 0; i < 4; ++i)
            gload16(A + (size_t)(m0 + arow[i]) * K + k0 + aq[i] * 4,
                    AsB + (i * 256 + wave * 64) * 16);
        #pragma unroll
        for (int i = 0; i < 2; ++i)
            gload16(Bt + (size_t)(n0 + brow[i]) * K + k0 + bq[i] * 8,
                    BsB + (i * 256 + wave * 64) * 16);

        __syncthreads();   // drains vmcnt: DMA complete before LDS reads

        short8 af[4], bfr[4];
        #pragma unroll
        for (int mi = 0; mi < 4; ++mi) {
            const int row = wr * 64 + mi * 16 + lrow;
            const int p0 = (2 * lkg) ^ (row & 7);
            const int p1 = (2 * lkg + 1) ^ (row & 7);
            f32x4 a0 = *reinterpret_cast<const f32x4*>(&As[row][p0 * 4]);
            f32x4 a1 = *reinterpret_cast<const f32x4*>(&As[row][p1 * 4]);
            uint4e u;
            u[0] = pk2(a0[0], a0[1]); u[1] = pk2(a0[2], a0[3]);
            u[2] = pk2(a1[0], a1[1]); u[3] = pk2(a1[2], a1[3]);
            af[mi] = *reinterpret_cast<short8*>(&u);
        }
        #pragma unroll
        for (int ni = 0; ni < 4; ++ni)
            bfr[ni] = *reinterpret_cast<const short8*>(&Bs[wc * 64 + ni * 16 + lrow][rslotB]);

        #pragma unroll
        for (int mi = 0; mi < 4; ++mi)
            #pragma unroll
            for (int ni = 0; ni < 4; ++ni)
                acc[mi][ni] = __builtin_amdgcn_mfma_f32_16x16x32_bf16(
                    af[mi], bfr[ni], acc[mi][ni], 0, 0, 0);

        __syncthreads();   // protect LDS before next stage
    }

    #pragma unroll
    for (int mi = 0; mi < 4; ++mi)
        #pragma unroll
        for (int ni = 0; ni < 4; ++ni)
            #pragma unroll
            for (int r = 0; r < 4; ++r)
                Cb[(size_t)(m0 + wr * 64 + mi * 16 + lkg * 4 + r) * NC
                   + (n0 + wc * 64 + ni * 16 + lrow)] = f2bf(acc[mi][ni][r]);
}

// ---------------- GEMM2: bf16 A/B via gload_lds, BK=64 dbuf (R8 path) ----------------

#define TM 128
#define TN 128
#define TK 64

__global__ __launch_bounds__(256) void gemm2_bf16(
    const unsigned short* __restrict__ Ab, const unsigned short* __restrict__ Bt,
    unsigned short* __restrict__ Cb, int M, int K, int Nc)
{
    __shared__ unsigned short As[2][TM][TK];   // 2 x 16 KB
    __shared__ unsigned short Bs[2][TN][TK];   // 2 x 16 KB

    const int tid  = threadIdx.x;
    const int lane = tid & 63;
    const int wave = tid >> 6;
    const int wr = wave >> 1, wc = wave & 1;
    const int lrow = lane & 15;
    const int lkg  = lane >> 4;

    const int per = gridDim.x / NXCD;
    const int newlin = (blockIdx.x % NXCD) * per + blockIdx.x / NXCD;
    const int ncb = Nc / TN;
    const int m0 = (newlin / ncb) * TM;
    const int n0 = (newlin % ncb) * TN;

    int srow[4], sq[4];
    #pragma unroll
    for (int i = 0; i < 4; ++i) {
        int s = i * 256 + wave * 64 + lane;
        srow[i] = s >> 3;
        sq[i] = (s & 7) ^ ((s >> 3) & 7);
    }

    char* AsB = (char*)&As[0][0][0];
    char* BsB = (char*)&Bs[0][0][0];

    auto stageOp = [&](const unsigned short* G, int rc0, int kt, char* opBase, int buf) {
        const int k0 = kt * TK;
        #pragma unroll
        for (int i = 0; i < 4; ++i)
            gload16(G + (size_t)(rc0 + srow[i]) * K + k0 + sq[i] * 8,
                    opBase + buf * 16384 + (i * 256 + wave * 64) * 16);
    };

    f32x4 acc[4][4] = {};

    stageOp(Bt, n0, 0, BsB, 0);
    stageOp(Ab, m0, 0, AsB, 0);
    __syncthreads();

    const int nk = K / TK;
    for (int kt = 0; kt < nk; ++kt) {
        const int cur = kt & 1, nxt = cur ^ 1;

        if (kt + 1 < nk) {
            stageOp(Bt, n0, kt + 1, BsB, nxt);
            stageOp(Ab, m0, kt + 1, AsB, nxt);
        }

        #pragma unroll
        for (int ks = 0; ks < 2; ++ks) {
            short8 af[4], bfr[4];
            #pragma unroll
            for (int mi = 0; mi < 4; ++mi) {
                const int row = wr * 64 + mi * 16 + lrow;
                const int qp = (ks * 4 + lkg) ^ (lrow & 7);
                af[mi] = *reinterpret_cast<const short8*>(&As[cur][row][qp * 8]);
            }
            #pragma unroll
            for (int ni = 0; ni < 4; ++ni) {
                const int row = wc * 64 + ni * 16 + lrow;
                const int qp = (ks * 4 + lkg) ^ (lrow & 7);
                bfr[ni] = *reinterpret_cast<const short8*>(&Bs[cur][row][qp * 8]);
            }
            #pragma unroll
            for (int mi = 0; mi < 4; ++mi)
                #pragma unroll
                for (int ni = 0; ni < 4; ++ni)
                    acc[mi][ni] = __builtin_amdgcn_mfma_f32_16x16x32_bf16(
                        af[mi], bfr[ni], acc[mi][ni], 0, 0, 0);
        }

        __syncthreads();
    }

    #pragma unroll
    for (int mi = 0; mi < 4; ++mi)
        #pragma unroll
        for (int ni = 0; ni < 4; ++ni)
            #pragma unroll
            for (int r = 0; r < 4; ++r)
                Cb[(size_t)(m0 + wr * 64 + mi * 16 + lkg * 4 + r) * Nc
                   + (n0 + wc * 64 + ni * 16 + lrow)] = f2bf(acc[mi][ni][r]);
}

// ---------------- CSR gather-aggregate (bf16 X), fused epilogues ----------------
// LAYER1: acc = sum iso[src]*X[src]; out_bf = bf16(elu(acc*isi + b1) * iso[node])
// else:   acc = sum X[src];          out_f  = acc*isi + b2

template<int DIM, bool LAYER1>
__global__ __launch_bounds__(256) void aggregate(
    const int* __restrict__ row_start, const int* __restrict__ eidx,
    const unsigned short* __restrict__ Xb, const float* __restrict__ isi,
    const float* __restrict__ iso, const float* __restrict__ bias,
    unsigned short* __restrict__ out_bf, float* __restrict__ out_f)
{
    constexpr int F = DIM / 64;           // 8 (HID) or 4 (OUTD)
    using VecT = typename VecSel<F>::T;
    const int node = blockIdx.x * 4 + (threadIdx.x >> 6);
    const int lane = threadIdx.x & 63;

    const int beg = row_start[node];
    const int end = row_start[node + 1];
    const unsigned short* base = Xb + lane * F;

    float acc[F] = {};
    int e = beg;
    for (; e + 3 < end; e += 4) {
        int i0 = eidx[e], i1 = eidx[e + 1], i2 = eidx[e + 2], i3 = eidx[e + 3];
        float s0 = 1.f, s1 = 1.f, s2 = 1.f, s3 = 1.f;
        if (LAYER1) { s0 = iso[i0]; s1 = iso[i1]; s2 = iso[i2]; s3 = iso[i3]; }
        VecT v0 = *reinterpret_cast<const VecT*>(base + (size_t)i0 * DIM);
        VecT v1 = *reinterpret_cast<const VecT*>(base + (size_t)i1 * DIM);
        VecT v2 = *reinterpret_cast<const VecT*>(base + (size_t)i2 * DIM);
        VecT v3 = *reinterpret_cast<const VecT*>(base + (size_t)i3 * DIM);
        #pragma unroll
        for (int f = 0; f < F; ++f) {
            if (LAYER1) {
                acc[f] = fmaf(s0, bf2f(v0[f]), acc[f]);
                acc[f] = fmaf(s1, bf2f(v1[f]), acc[f]);
                acc[f] = fmaf(s2, bf2f(v2[f]), acc[f]);
                acc[f] = fmaf(s3, bf2f(v3[f]), acc[f]);
            } else {
                acc[f] += bf2f(v0[f]); acc[f] += bf2f(v1[f]);
                acc[f] += bf2f(v2[f]); acc[f] += bf2f(v3[f]);
            }
        }
    }
    for (; e < end; ++e) {
        int i0 = eidx[e];
        float s0 = LAYER1 ? iso[i0] : 1.f;
        VecT v0 = *reinterpret_cast<const VecT*>(base + (size_t)i0 * DIM);
        #pragma unroll
        for (int f = 0; f < F; ++f)
            acc[f] = LAYER1 ? fmaf(s0, bf2f(v0[f]), acc[f]) : acc[f] + bf2f(v0[f]);
    }

    const float si = isi[node];
    float bv[F];
    #pragma unroll
    for (int q = 0; q < F / 4; ++q)
        *reinterpret_cast<float4*>(&bv[q * 4]) =
            *reinterpret_cast<const float4*>(bias + lane * F + q * 4);

    if (LAYER1) {
        const float so = iso[node];
        short8 o;
        #pragma unroll
        for (int f = 0; f < F; ++f) {
            float v = acc[f] * si + bv[f];
            v = v > 0.f ? v : expm1f(v);
            o[f] = (short)f2bf(v * so);
        }
        *reinterpret_cast<short8*>(out_bf + (size_t)node * DIM + lane * F) = o;
    } else {
        #pragma unroll
        for (int q = 0; q < F / 4; ++q) {
            float4 v = make_float4(acc[q * 4 + 0] * si + bv[q * 4 + 0],
                                   acc[q * 4 + 1] * si + bv[q * 4 + 1],
                                   acc[q * 4 + 2] * si + bv[q * 4 + 2],
                                   acc[q * 4 + 3] * si + bv[q * 4 + 3]);
            *reinterpret_cast<float4*>(out_f + (size_t)node * DIM + lane * F + q * 4) = v;
        }
    }
}

// ---------------- launch ----------------

extern "C" void kernel_launch(void* const* d_in, const int* in_sizes, int n_in,
                              void* d_out, int out_size, void* d_ws, size_t ws_size,
                              hipStream_t stream) {
    const float* h  = (const float*)d_in[0];
    const float* W1 = (const float*)d_in[1];
    const float* b1 = (const float*)d_in[2];
    const float* W2 = (const float*)d_in[3];
    const float* b2 = (const float*)d_in[4];
    const int*   src = (const int*)d_in[5];
    const int*   dst = (const int*)d_in[6];

    const int N = in_sizes[0] / IN_DIM;   // 65536
    const int E = in_sizes[5];            // 524288
    float* out = (float*)d_out;

    // ---- workspace layout ----
    int* dego      = (int*)d_ws;                   // N
    int* degi      = dego + N;                     // N
    int* excl      = degi + N;                     // N
    int* partials  = excl + N;                     // 256
    int* row_start = partials + 256;               // N+1 (pad to N+64)
    int* cursor    = row_start + N + 64;           // N
    int* eidx      = cursor + N;                   // E
    float* iso     = (float*)(eidx + E);           // N
    float* isi     = iso + N;                      // N
    unsigned short* W1t = (unsigned short*)(isi + N);      // IN_DIM*HID
    unsigned short* W2t = W1t + (size_t)IN_DIM * HID;      // HID*OUTD
    unsigned short* X1b = W2t + (size_t)HID * OUTD;        // N*HID bf16 (67MB)
    unsigned short* X2b = X1b;                             // alias (X1 dead before gemm2 write)
    unsigned short* R2h = X1b + (size_t)N * HID;           // N*HID bf16 (67MB) — x1s

    hipMemsetAsync(dego, 0, sizeof(int) * (size_t)2 * N, stream);

    deg_kernel<<<(E + 255) / 256, 256, 0, stream>>>(src, dst, dego, degi, E);
    invsqrt_kernel<<<(N + 255) / 256, 256, 0, stream>>>(dego, degi, iso, isi, N);

    // CSR by dst
    scan_block<<<N / 256, 256, 0, stream>>>(degi, excl, partials);
    scan_partials<<<1, 256, 0, stream>>>(partials);
    scan_add<<<N / 256, 256, 0, stream>>>(excl, partials, degi, row_start, cursor, N);
    csr_fill<<<(E + 255) / 256, 256, 0, stream>>>(src, dst, cursor, eidx, E);

    // weights -> bf16 transposed
    transpose_cvt<<<(IN_DIM * HID + 255) / 256, 256, 0, stream>>>(W1, W1t, IN_DIM, HID);
    transpose_cvt<<<(HID * OUTD + 255) / 256, 256, 0, stream>>>(W2, W2t, HID, OUTD);

    // Layer 1: X1b = bf16(h @ W1) [A via DMA, cvt in MFMA phase];
    //          aggregate applies iso[src] during gather
    gemm1_f32lds<<<(N / 128) * (HID / 128), 256, 0, stream>>>(h, W1t, X1b, N);
    aggregate<HID, true><<<N / 4, 256, 0, stream>>>(
        row_start, eidx, X1b, isi, iso, b1, R2h, nullptr);

    // Layer 2: X2b = bf16(R2h @ W2) ; out = agg(X2b)*isi + b2
    gemm2_bf16<<<(N / TM) * (OUTD / TN), 256, 0, stream>>>(
        R2h, W2t, X2b, N, HID, OUTD);
    aggregate<OUTD, false><<<N / 4, 256, 0, stream>>>(
        row_start, eidx, X2b, isi, iso, b2, nullptr, out);
}

// Round 15
// 402.196 us; speedup vs baseline: 1.6135x; 1.0004x over previous
//
#include <hip/hip_runtime.h>
#include <hip/hip_bf16.h>

#define IN_DIM 1024
#define HID 512
#define OUTD 256

typedef __attribute__((ext_vector_type(8))) short short8;
typedef __attribute__((ext_vector_type(4))) float f32x4;
typedef __attribute__((ext_vector_type(8))) unsigned short ushort8e;
typedef __attribute__((ext_vector_type(4))) unsigned short ushort4e;
typedef __attribute__((ext_vector_type(4))) unsigned int uint4e;

template<int F> struct VecSel;
template<> struct VecSel<8> { using T = ushort8e; };
template<> struct VecSel<4> { using T = ushort4e; };

// ---------------- helpers ----------------

__device__ inline unsigned short f2bf(float f) {
    union { float f; unsigned u; } v; v.f = f;
    unsigned r = (v.u + 0x7FFF + ((v.u >> 16) & 1)) >> 16;  // RNE
    return (unsigned short)r;
}

__device__ inline float bf2f(unsigned short u) {
    union { unsigned u; float f; } v; v.u = ((unsigned)u) << 16; return v.f;
}

// two f32 -> packed bf16x2: round-half-up (add 0x8000) + byte-perm pack
__device__ inline unsigned pk2(float a, float b) {
    unsigned ua = __float_as_uint(a) + 0x8000u;
    unsigned ub = __float_as_uint(b) + 0x8000u;
#if __has_builtin(__builtin_amdgcn_perm)
    return __builtin_amdgcn_perm(ub, ua, 0x07060302u);   // lo = ua>>16, hi = ub>>16
#else
    return (ua >> 16) | (ub & 0xFFFF0000u);
#endif
}

__device__ inline void gload16(const void* g, void* l) {
    __builtin_amdgcn_global_load_lds(
        (const __attribute__((address_space(1))) void*)g,
        (__attribute__((address_space(3))) void*)l, 16, 0, 0);
}

// ---------------- degree / norm ----------------

__global__ void deg_kernel(const int* __restrict__ src, const int* __restrict__ dst,
                           int* __restrict__ dego, int* __restrict__ degi, int E) {
    int i = blockIdx.x * blockDim.x + threadIdx.x;
    if (i < E) {
        atomicAdd(&dego[src[i]], 1);
        atomicAdd(&degi[dst[i]], 1);
    }
}

__global__ void invsqrt_kernel(const int* __restrict__ dego, const int* __restrict__ degi,
                               float* __restrict__ iso, float* __restrict__ isi, int n) {
    int i = blockIdx.x * blockDim.x + threadIdx.x;
    if (i < n) {
        iso[i] = rsqrtf(fmaxf((float)dego[i], 1.0f));
        isi[i] = rsqrtf(fmaxf((float)degi[i], 1.0f));
    }
}

// ---------------- exclusive scan over N=65536 (256 blocks x 256) ----------------

__global__ __launch_bounds__(256) void scan_block(const int* __restrict__ deg,
                                                  int* __restrict__ excl,
                                                  int* __restrict__ partials) {
    __shared__ int tmp[256];
    int tid = threadIdx.x;
    int i = blockIdx.x * 256 + tid;
    int v = deg[i];
    tmp[tid] = v;
    __syncthreads();
    #pragma unroll
    for (int off = 1; off < 256; off <<= 1) {
        int t = (tid >= off) ? tmp[tid - off] : 0;
        __syncthreads();
        tmp[tid] += t;
        __syncthreads();
    }
    excl[i] = tmp[tid] - v;
    if (tid == 255) partials[blockIdx.x] = tmp[255];
}

__global__ __launch_bounds__(256) void scan_partials(int* __restrict__ partials) {
    __shared__ int tmp[256];
    int tid = threadIdx.x;
    int v = partials[tid];
    tmp[tid] = v;
    __syncthreads();
    #pragma unroll
    for (int off = 1; off < 256; off <<= 1) {
        int t = (tid >= off) ? tmp[tid - off] : 0;
        __syncthreads();
        tmp[tid] += t;
        __syncthreads();
    }
    partials[tid] = tmp[tid] - v;   // exclusive
}

__global__ __launch_bounds__(256) void scan_add(const int* __restrict__ excl,
                                                const int* __restrict__ partials,
                                                const int* __restrict__ deg,
                                                int* __restrict__ row_start,
                                                int* __restrict__ cursor, int n) {
    int i = blockIdx.x * 256 + threadIdx.x;
    int v = excl[i] + partials[blockIdx.x];
    row_start[i] = v;
    cursor[i] = v;
    if (i == n - 1) row_start[n] = v + deg[i];
}

__global__ void csr_fill(const int* __restrict__ src, const int* __restrict__ dst,
                         int* __restrict__ cursor, int* __restrict__ eidx, int E) {
    int e = blockIdx.x * blockDim.x + threadIdx.x;
    if (e < E) {
        int pos = atomicAdd(&cursor[dst[e]], 1);
        eidx[pos] = src[e];
    }
}

// ---------------- weight transpose+cvt ----------------

__global__ void transpose_cvt(const float* __restrict__ W, unsigned short* __restrict__ Wt,
                              int K, int N) {
    int i = blockIdx.x * 256 + threadIdx.x;
    if (i < N * K) {
        int n = i / K, k = i - n * K;
        Wt[i] = f2bf(W[(size_t)k * N + n]);
    }
}

// ---------------- GEMM1: A f32 via DMA into HOLE-PADDED LDS (144B rows) ----------
// C[M,HID] = bf16( A[M,IN_DIM] @ Bt[HID,IN_DIM]^T ); iso-scale applied in aggregate.
// A tile: 128 rows x 9 slots of 16B (8 data quads + 1 hole) = 144B rows.
// row*144 = row*36 dwords -> rows rotate banks by 4 -> fragment reads
// (row*144 + lkg*32) hit 2 lanes/bank-group per 16-lane phase = conflict-free,
// while keeping the pure global_load_lds DMA staging (linear dest).
// Conversion f32->bf16 (pk2) in the MFMA phase (VALU co-issues with matrix pipe).

#define NXCD 8

__global__ __launch_bounds__(256) void gemm1_f32lds(
    const float* __restrict__ A, const unsigned short* __restrict__ Bt,
    unsigned short* __restrict__ Cb, int M)
{
    constexpr int K  = IN_DIM;   // 1024
    constexpr int NC = HID;      // 512
    __shared__ float          As[128 * 36];  // 18 KB (144B rows, hole-padded)
    __shared__ unsigned short Bs[128][32];   // 8 KB

    const int tid  = threadIdx.x;
    const int lane = tid & 63;
    const int wave = tid >> 6;
    const int wr = wave >> 1, wc = wave & 1;
    const int lrow = lane & 15;
    const int lkg  = lane >> 4;

    // XCD swizzle (bijective: 2048 % 8 == 0)
    const int per = gridDim.x / NXCD;
    const int newlin = (blockIdx.x % NXCD) * per + blockIdx.x / NXCD;
    const int ncb = NC / 128;                 // 4
    const int m0 = (newlin / ncb) * 128;
    const int n0 = (newlin % ncb) * 128;

    char* AsB = (char*)&As[0];
    char* BsB = (char*)&Bs[0][0];

    // A slots: 1152 x 16B; slot s -> row = s/9, quad q = s%9 (q==8 is the hole)
    int arow[5], aq[5];
    #pragma unroll
    for (int i = 0; i < 5; ++i) {
        int s = i * 256 + wave * 64 + lane;
        int r = s / 9;
        int q = s - r * 9;
        arow[i] = r;
        aq[i] = (q == 8) ? 0 : q;   // hole: load row's quad 0 (never read)
    }
    // B slots: 512 x 16B; slot s -> row s>>2, src quad = (s&3) ^ ((row>>1)&3)
    int brow[2], bq[2];
    #pragma unroll
    for (int i = 0; i < 2; ++i) {
        int s = i * 256 + wave * 64 + lane;
        brow[i] = s >> 2;
        bq[i] = (s & 3) ^ ((s >> 3) & 3);
    }

    const int rslotB = (lkg ^ ((lrow >> 1) & 3)) * 8;

    f32x4 acc[4][4] = {};

    for (int kt = 0; kt < K / 32; ++kt) {
        const int k0 = kt * 32;

        #pragma unroll
        for (int i = 0; i < 4; ++i)
            gload16(A + (size_t)(m0 + arow[i]) * K + k0 + aq[i] * 4,
                    AsB + (i * 256 + wave * 64) * 16);
        if (wave < 2)   // slots 1024..1151 (wave-uniform branch)
            gload16(A + (size_t)(m0 + arow[4]) * K + k0 + aq[4] * 4,
                    AsB + (4 * 256 + wave * 64) * 16);
        #pragma unroll
        for (int i = 0; i < 2; ++i)
            gload16(Bt + (size_t)(n0 + brow[i]) * K + k0 + bq[i] * 8,
                    BsB + (i * 256 + wave * 64) * 16);

        __syncthreads();   // drains vmcnt: DMA complete before LDS reads

        short8 af[4], bfr[4];
        #pragma unroll
        for (int mi = 0; mi < 4; ++mi) {
            const int row = wr * 64 + mi * 16 + lrow;
            const char* rb = AsB + row * 144 + lkg * 32;
            f32x4 a0 = *reinterpret_cast<const f32x4*>(rb);
            f32x4 a1 = *reinterpret_cast<const f32x4*>(rb + 16);
            uint4e u;
            u[0] = pk2(a0[0], a0[1]); u[1] = pk2(a0[2], a0[3]);
            u[2] = pk2(a1[0], a1[1]); u[3] = pk2(a1[2], a1[3]);
            af[mi] = *reinterpret_cast<short8*>(&u);
        }
        #pragma unroll
        for (int ni = 0; ni < 4; ++ni)
            bfr[ni] = *reinterpret_cast<const short8*>(&Bs[wc * 64 + ni * 16 + lrow][rslotB]);

        #pragma unroll
        for (int mi = 0; mi < 4; ++mi)
            #pragma unroll
            for (int ni = 0; ni < 4; ++ni)
                acc[mi][ni] = __builtin_amdgcn_mfma_f32_16x16x32_bf16(
                    af[mi], bfr[ni], acc[mi][ni], 0, 0, 0);

        __syncthreads();   // protect LDS before next stage
    }

    #pragma unroll
    for (int mi = 0; mi < 4; ++mi)
        #pragma unroll
        for (int ni = 0; ni < 4; ++ni)
            #pragma unroll
            for (int r = 0; r < 4; ++r)
                Cb[(size_t)(m0 + wr * 64 + mi * 16 + lkg * 4 + r) * NC
                   + (n0 + wc * 64 + ni * 16 + lrow)] = f2bf(acc[mi][ni][r]);
}

// ---------------- GEMM2: bf16 A/B via gload_lds, BK=64 dbuf (R8 path) ----------------

#define TM 128
#define TN 128
#define TK 64

__global__ __launch_bounds__(256) void gemm2_bf16(
    const unsigned short* __restrict__ Ab, const unsigned short* __restrict__ Bt,
    unsigned short* __restrict__ Cb, int M, int K, int Nc)
{
    __shared__ unsigned short As[2][TM][TK];   // 2 x 16 KB
    __shared__ unsigned short Bs[2][TN][TK];   // 2 x 16 KB

    const int tid  = threadIdx.x;
    const int lane = tid & 63;
    const int wave = tid >> 6;
    const int wr = wave >> 1, wc = wave & 1;
    const int lrow = lane & 15;
    const int lkg  = lane >> 4;

    const int per = gridDim.x / NXCD;
    const int newlin = (blockIdx.x % NXCD) * per + blockIdx.x / NXCD;
    const int ncb = Nc / TN;
    const int m0 = (newlin / ncb) * TM;
    const int n0 = (newlin % ncb) * TN;

    int srow[4], sq[4];
    #pragma unroll
    for (int i = 0; i < 4; ++i) {
        int s = i * 256 + wave * 64 + lane;
        srow[i] = s >> 3;
        sq[i] = (s & 7) ^ ((s >> 3) & 7);
    }

    char* AsB = (char*)&As[0][0][0];
    char* BsB = (char*)&Bs[0][0][0];

    auto stageOp = [&](const unsigned short* G, int rc0, int kt, char* opBase, int buf) {
        const int k0 = kt * TK;
        #pragma unroll
        for (int i = 0; i < 4; ++i)
            gload16(G + (size_t)(rc0 + srow[i]) * K + k0 + sq[i] * 8,
                    opBase + buf * 16384 + (i * 256 + wave * 64) * 16);
    };

    f32x4 acc[4][4] = {};

    stageOp(Bt, n0, 0, BsB, 0);
    stageOp(Ab, m0, 0, AsB, 0);
    __syncthreads();

    const int nk = K / TK;
    for (int kt = 0; kt < nk; ++kt) {
        const int cur = kt & 1, nxt = cur ^ 1;

        if (kt + 1 < nk) {
            stageOp(Bt, n0, kt + 1, BsB, nxt);
            stageOp(Ab, m0, kt + 1, AsB, nxt);
        }

        #pragma unroll
        for (int ks = 0; ks < 2; ++ks) {
            short8 af[4], bfr[4];
            #pragma unroll
            for (int mi = 0; mi < 4; ++mi) {
                const int row = wr * 64 + mi * 16 + lrow;
                const int qp = (ks * 4 + lkg) ^ (lrow & 7);
                af[mi] = *reinterpret_cast<const short8*>(&As[cur][row][qp * 8]);
            }
            #pragma unroll
            for (int ni = 0; ni < 4; ++ni) {
                const int row = wc * 64 + ni * 16 + lrow;
                const int qp = (ks * 4 + lkg) ^ (lrow & 7);
                bfr[ni] = *reinterpret_cast<const short8*>(&Bs[cur][row][qp * 8]);
            }
            #pragma unroll
            for (int mi = 0; mi < 4; ++mi)
                #pragma unroll
                for (int ni = 0; ni < 4; ++ni)
                    acc[mi][ni] = __builtin_amdgcn_mfma_f32_16x16x32_bf16(
                        af[mi], bfr[ni], acc[mi][ni], 0, 0, 0);
        }

        __syncthreads();
    }

    #pragma unroll
    for (int mi = 0; mi < 4; ++mi)
        #pragma unroll
        for (int ni = 0; ni < 4; ++ni)
            #pragma unroll
            for (int r = 0; r < 4; ++r)
                Cb[(size_t)(m0 + wr * 64 + mi * 16 + lkg * 4 + r) * Nc
                   + (n0 + wc * 64 + ni * 16 + lrow)] = f2bf(acc[mi][ni][r]);
}

// ---------------- CSR gather-aggregate (bf16 X), fused epilogues ----------------
// LAYER1: acc = sum iso[src]*X[src]; out_bf = bf16(elu(acc*isi + b1) * iso[node])
// else:   acc = sum X[src];          out_f  = acc*isi + b2

template<int DIM, bool LAYER1>
__global__ __launch_bounds__(256) void aggregate(
    const int* __restrict__ row_start, const int* __restrict__ eidx,
    const unsigned short* __restrict__ Xb, const float* __restrict__ isi,
    const float* __restrict__ iso, const float* __restrict__ bias,
    unsigned short* __restrict__ out_bf, float* __restrict__ out_f)
{
    constexpr int F = DIM / 64;           // 8 (HID) or 4 (OUTD)
    using VecT = typename VecSel<F>::T;
    const int node = blockIdx.x * 4 + (threadIdx.x >> 6);
    const int lane = threadIdx.x & 63;

    const int beg = row_start[node];
    const int end = row_start[node + 1];
    const unsigned short* base = Xb + lane * F;

    float acc[F] = {};
    int e = beg;
    for (; e + 3 < end; e += 4) {
        int i0 = eidx[e], i1 = eidx[e + 1], i2 = eidx[e + 2], i3 = eidx[e + 3];
        float s0 = 1.f, s1 = 1.f, s2 = 1.f, s3 = 1.f;
        if (LAYER1) { s0 = iso[i0]; s1 = iso[i1]; s2 = iso[i2]; s3 = iso[i3]; }
        VecT v0 = *reinterpret_cast<const VecT*>(base + (size_t)i0 * DIM);
        VecT v1 = *reinterpret_cast<const VecT*>(base + (size_t)i1 * DIM);
        VecT v2 = *reinterpret_cast<const VecT*>(base + (size_t)i2 * DIM);
        VecT v3 = *reinterpret_cast<const VecT*>(base + (size_t)i3 * DIM);
        #pragma unroll
        for (int f = 0; f < F; ++f) {
            if (LAYER1) {
                acc[f] = fmaf(s0, bf2f(v0[f]), acc[f]);
                acc[f] = fmaf(s1, bf2f(v1[f]), acc[f]);
                acc[f] = fmaf(s2, bf2f(v2[f]), acc[f]);
                acc[f] = fmaf(s3, bf2f(v3[f]), acc[f]);
            } else {
                acc[f] += bf2f(v0[f]); acc[f] += bf2f(v1[f]);
                acc[f] += bf2f(v2[f]); acc[f] += bf2f(v3[f]);
            }
        }
    }
    for (; e < end; ++e) {
        int i0 = eidx[e];
        float s0 = LAYER1 ? iso[i0] : 1.f;
        VecT v0 = *reinterpret_cast<const VecT*>(base + (size_t)i0 * DIM);
        #pragma unroll
        for (int f = 0; f < F; ++f)
            acc[f] = LAYER1 ? fmaf(s0, bf2f(v0[f]), acc[f]) : acc[f] + bf2f(v0[f]);
    }

    const float si = isi[node];
    float bv[F];
    #pragma unroll
    for (int q = 0; q < F / 4; ++q)
        *reinterpret_cast<float4*>(&bv[q * 4]) =
            *reinterpret_cast<const float4*>(bias + lane * F + q * 4);

    if (LAYER1) {
        const float so = iso[node];
        short8 o;
        #pragma unroll
        for (int f = 0; f < F; ++f) {
            float v = acc[f] * si + bv[f];
            v = v > 0.f ? v : expm1f(v);
            o[f] = (short)f2bf(v * so);
        }
        *reinterpret_cast<short8*>(out_bf + (size_t)node * DIM + lane * F) = o;
    } else {
        #pragma unroll
        for (int q = 0; q < F / 4; ++q) {
            float4 v = make_float4(acc[q * 4 + 0] * si + bv[q * 4 + 0],
                                   acc[q * 4 + 1] * si + bv[q * 4 + 1],
                                   acc[q * 4 + 2] * si + bv[q * 4 + 2],
                                   acc[q * 4 + 3] * si + bv[q * 4 + 3]);
            *reinterpret_cast<float4*>(out_f + (size_t)node * DIM + lane * F + q * 4) = v;
        }
    }
}

// ---------------- launch ----------------

extern "C" void kernel_launch(void* const* d_in, const int* in_sizes, int n_in,
                              void* d_out, int out_size, void* d_ws, size_t ws_size,
                              hipStream_t stream) {
    const float* h  = (const float*)d_in[0];
    const float* W1 = (const float*)d_in[1];
    const float* b1 = (const float*)d_in[2];
    const float* W2 = (const float*)d_in[3];
    const float* b2 = (const float*)d_in[4];
    const int*   src = (const int*)d_in[5];
    const int*   dst = (const int*)d_in[6];

    const int N = in_sizes[0] / IN_DIM;   // 65536
    const int E = in_sizes[5];            // 524288
    float* out = (float*)d_out;

    // ---- workspace layout ----
    int* dego      = (int*)d_ws;                   // N
    int* degi      = dego + N;                     // N
    int* excl      = degi + N;                     // N
    int* partials  = excl + N;                     // 256
    int* row_start = partials + 256;               // N+1 (pad to N+64)
    int* cursor    = row_start + N + 64;           // N
    int* eidx      = cursor + N;                   // E
    float* iso     = (float*)(eidx + E);           // N
    float* isi     = iso + N;                      // N
    unsigned short* W1t = (unsigned short*)(isi + N);      // IN_DIM*HID
    unsigned short* W2t = W1t + (size_t)IN_DIM * HID;      // HID*OUTD
    unsigned short* X1b = W2t + (size_t)HID * OUTD;        // N*HID bf16 (67MB)
    unsigned short* X2b = X1b;                             // alias (X1 dead before gemm2 write)
    unsigned short* R2h = X1b + (size_t)N * HID;           // N*HID bf16 (67MB) — x1s

    hipMemsetAsync(dego, 0, sizeof(int) * (size_t)2 * N, stream);

    deg_kernel<<<(E + 255) / 256, 256, 0, stream>>>(src, dst, dego, degi, E);
    invsqrt_kernel<<<(N + 255) / 256, 256, 0, stream>>>(dego, degi, iso, isi, N);

    // CSR by dst
    scan_block<<<N / 256, 256, 0, stream>>>(degi, excl, partials);
    scan_partials<<<1, 256, 0, stream>>>(partials);
    scan_add<<<N / 256, 256, 0, stream>>>(excl, partials, degi, row_start, cursor, N);
    csr_fill<<<(E + 255) / 256, 256, 0, stream>>>(src, dst, cursor, eidx, E);

    // weights -> bf16 transposed
    transpose_cvt<<<(IN_DIM * HID + 255) / 256, 256, 0, stream>>>(W1, W1t, IN_DIM, HID);
    transpose_cvt<<<(HID * OUTD + 255) / 256, 256, 0, stream>>>(W2, W2t, HID, OUTD);

    // Layer 1: X1b = bf16(h @ W1) [A via DMA into hole-padded LDS, cvt in MFMA phase];
    //          aggregate applies iso[src] during gather
    gemm1_f32lds<<<(N / 128) * (HID / 128), 256, 0, stream>>>(h, W1t, X1b, N);
    aggregate<HID, true><<<N / 4, 256, 0, stream>>>(
        row_start, eidx, X1b, isi, iso, b1, R2h, nullptr);

    // Layer 2: X2b = bf16(R2h @ W2) ; out = agg(X2b)*isi + b2
    gemm2_bf16<<<(N / TM) * (OUTD / TN), 256, 0, stream>>>(
        R2h, W2t, X2b, N, HID, OUTD);
    aggregate<OUTD, false><<<N / 4, 256, 0, stream>>>(
        row_start, eidx, X2b, isi, iso, b2, nullptr, out);
}

// Round 16
// 391.732 us; speedup vs baseline: 1.6566x; 1.0267x over previous
//
#include <hip/hip_runtime.h>
#include <hip/hip_bf16.h>

#define IN_DIM 1024
#define HID 512
#define OUTD 256

typedef __attribute__((ext_vector_type(8))) short short8;
typedef __attribute__((ext_vector_type(4))) float f32x4;
typedef __attribute__((ext_vector_type(8))) unsigned short ushort8e;
typedef __attribute__((ext_vector_type(4))) unsigned short ushort4e;
typedef __attribute__((ext_vector_type(4))) unsigned int uint4e;

template<int F> struct VecSel;
template<> struct VecSel<8> { using T = ushort8e; };
template<> struct VecSel<4> { using T = ushort4e; };

// ---------------- helpers ----------------

__device__ inline unsigned short f2bf(float f) {
    union { float f; unsigned u; } v; v.f = f;
    unsigned r = (v.u + 0x7FFF + ((v.u >> 16) & 1)) >> 16;  // RNE
    return (unsigned short)r;
}

__device__ inline float bf2f(unsigned short u) {
    union { unsigned u; float f; } v; v.u = ((unsigned)u) << 16; return v.f;
}

// two f32 -> packed bf16x2: round-half-up (add 0x8000) + byte-perm pack
__device__ inline unsigned pk2(float a, float b) {
    unsigned ua = __float_as_uint(a) + 0x8000u;
    unsigned ub = __float_as_uint(b) + 0x8000u;
#if __has_builtin(__builtin_amdgcn_perm)
    return __builtin_amdgcn_perm(ub, ua, 0x07060302u);   // lo = ua>>16, hi = ub>>16
#else
    return (ua >> 16) | (ub & 0xFFFF0000u);
#endif
}

__device__ inline void gload16(const void* g, void* l) {
    __builtin_amdgcn_global_load_lds(
        (const __attribute__((address_space(1))) void*)g,
        (__attribute__((address_space(3))) void*)l, 16, 0, 0);
}

// ---------------- degree / norm ----------------

__global__ void deg_kernel(const int* __restrict__ src, const int* __restrict__ dst,
                           int* __restrict__ dego, int* __restrict__ degi, int E) {
    int i = blockIdx.x * blockDim.x + threadIdx.x;
    if (i < E) {
        atomicAdd(&dego[src[i]], 1);
        atomicAdd(&degi[dst[i]], 1);
    }
}

__global__ void invsqrt_kernel(const int* __restrict__ dego, const int* __restrict__ degi,
                               float* __restrict__ iso, float* __restrict__ isi, int n) {
    int i = blockIdx.x * blockDim.x + threadIdx.x;
    if (i < n) {
        iso[i] = rsqrtf(fmaxf((float)dego[i], 1.0f));
        isi[i] = rsqrtf(fmaxf((float)degi[i], 1.0f));
    }
}

// ---------------- exclusive scan over N=65536 (256 blocks x 256) ----------------

__global__ __launch_bounds__(256) void scan_block(const int* __restrict__ deg,
                                                  int* __restrict__ excl,
                                                  int* __restrict__ partials) {
    __shared__ int tmp[256];
    int tid = threadIdx.x;
    int i = blockIdx.x * 256 + tid;
    int v = deg[i];
    tmp[tid] = v;
    __syncthreads();
    #pragma unroll
    for (int off = 1; off < 256; off <<= 1) {
        int t = (tid >= off) ? tmp[tid - off] : 0;
        __syncthreads();
        tmp[tid] += t;
        __syncthreads();
    }
    excl[i] = tmp[tid] - v;
    if (tid == 255) partials[blockIdx.x] = tmp[255];
}

__global__ __launch_bounds__(256) void scan_partials(int* __restrict__ partials) {
    __shared__ int tmp[256];
    int tid = threadIdx.x;
    int v = partials[tid];
    tmp[tid] = v;
    __syncthreads();
    #pragma unroll
    for (int off = 1; off < 256; off <<= 1) {
        int t = (tid >= off) ? tmp[tid - off] : 0;
        __syncthreads();
        tmp[tid] += t;
        __syncthreads();
    }
    partials[tid] = tmp[tid] - v;   // exclusive
}

__global__ __launch_bounds__(256) void scan_add(const int* __restrict__ excl,
                                                const int* __restrict__ partials,
                                                const int* __restrict__ deg,
                                                int* __restrict__ row_start,
                                                int* __restrict__ cursor, int n) {
    int i = blockIdx.x * 256 + threadIdx.x;
    int v = excl[i] + partials[blockIdx.x];
    row_start[i] = v;
    cursor[i] = v;
    if (i == n - 1) row_start[n] = v + deg[i];
}

__global__ void csr_fill(const int* __restrict__ src, const int* __restrict__ dst,
                         int* __restrict__ cursor, int* __restrict__ eidx, int E) {
    int e = blockIdx.x * blockDim.x + threadIdx.x;
    if (e < E) {
        int pos = atomicAdd(&cursor[dst[e]], 1);
        eidx[pos] = src[e];
    }
}

// ---------------- weight transpose+cvt: 32x32 LDS tile, coalesced both sides ----

__global__ __launch_bounds__(256) void transpose_cvt_tiled(
    const float* __restrict__ W, unsigned short* __restrict__ Wt, int K, int N)
{
    __shared__ unsigned short tile[32][33];   // +1 pad: column reads conflict-free
    const int tx = threadIdx.x & 31;
    const int ty = threadIdx.x >> 5;          // 0..7
    const int n0 = blockIdx.x * 32;
    const int k0 = blockIdx.y * 32;

    #pragma unroll
    for (int j = 0; j < 4; ++j) {
        int k = ty + j * 8;
        tile[k][tx] = f2bf(W[(size_t)(k0 + k) * N + n0 + tx]);   // coalesced read
    }
    __syncthreads();
    #pragma unroll
    for (int j = 0; j < 4; ++j) {
        int n = ty + j * 8;
        Wt[(size_t)(n0 + n) * K + k0 + tx] = tile[tx][n];        // coalesced write
    }
}

// ---------------- GEMM1: A f32 via DMA (hole-padded LDS), occupancy-forced ----------
// C[M,HID] = bf16( A[M,IN_DIM] @ Bt[HID,IN_DIM]^T ); iso-scale applied in aggregate.
// __launch_bounds__(256,4): cap unified regs at 128 -> 4 waves/SIMD (~4 blocks/CU),
// the R8-vs-gemm2 comparison's diagnosed limiter (2.4 blocks/CU -> 3300cy/step
// vs 4 blocks/CU -> 1400cy/step on the identical structure).

#define NXCD 8

__global__ __launch_bounds__(256, 4) void gemm1_f32lds(
    const float* __restrict__ A, const unsigned short* __restrict__ Bt,
    unsigned short* __restrict__ Cb, int M)
{
    constexpr int K  = IN_DIM;   // 1024
    constexpr int NC = HID;      // 512
    __shared__ float          As[128 * 36];  // 18 KB (144B rows, hole-padded)
    __shared__ unsigned short Bs[128][32];   // 8 KB

    const int tid  = threadIdx.x;
    const int lane = tid & 63;
    const int wave = tid >> 6;
    const int wr = wave >> 1, wc = wave & 1;
    const int lrow = lane & 15;
    const int lkg  = lane >> 4;

    // XCD swizzle (bijective: 2048 % 8 == 0)
    const int per = gridDim.x / NXCD;
    const int newlin = (blockIdx.x % NXCD) * per + blockIdx.x / NXCD;
    const int ncb = NC / 128;                 // 4
    const int m0 = (newlin / ncb) * 128;
    const int n0 = (newlin % ncb) * 128;

    char* AsB = (char*)&As[0];
    char* BsB = (char*)&Bs[0][0];

    // A slots: 1152 x 16B; slot s -> row = s/9, quad q = s%9 (q==8 is the hole)
    int arow[5], aq[5];
    #pragma unroll
    for (int i = 0; i < 5; ++i) {
        int s = i * 256 + wave * 64 + lane;
        int r = s / 9;
        int q = s - r * 9;
        arow[i] = r;
        aq[i] = (q == 8) ? 0 : q;   // hole: load row's quad 0 (never read)
    }
    // B slots: 512 x 16B; slot s -> row s>>2, src quad = (s&3) ^ ((row>>1)&3)
    int brow[2], bq[2];
    #pragma unroll
    for (int i = 0; i < 2; ++i) {
        int s = i * 256 + wave * 64 + lane;
        brow[i] = s >> 2;
        bq[i] = (s & 3) ^ ((s >> 3) & 3);
    }

    const int rslotB = (lkg ^ ((lrow >> 1) & 3)) * 8;

    f32x4 acc[4][4] = {};

    for (int kt = 0; kt < K / 32; ++kt) {
        const int k0 = kt * 32;

        #pragma unroll
        for (int i = 0; i < 4; ++i)
            gload16(A + (size_t)(m0 + arow[i]) * K + k0 + aq[i] * 4,
                    AsB + (i * 256 + wave * 64) * 16);
        if (wave < 2)   // slots 1024..1151 (wave-uniform branch)
            gload16(A + (size_t)(m0 + arow[4]) * K + k0 + aq[4] * 4,
                    AsB + (4 * 256 + wave * 64) * 16);
        #pragma unroll
        for (int i = 0; i < 2; ++i)
            gload16(Bt + (size_t)(n0 + brow[i]) * K + k0 + bq[i] * 8,
                    BsB + (i * 256 + wave * 64) * 16);

        __syncthreads();   // drains vmcnt: DMA complete before LDS reads

        short8 af[4], bfr[4];
        #pragma unroll
        for (int mi = 0; mi < 4; ++mi) {
            const int row = wr * 64 + mi * 16 + lrow;
            const char* rb = AsB + row * 144 + lkg * 32;
            f32x4 a0 = *reinterpret_cast<const f32x4*>(rb);
            f32x4 a1 = *reinterpret_cast<const f32x4*>(rb + 16);
            uint4e u;
            u[0] = pk2(a0[0], a0[1]); u[1] = pk2(a0[2], a0[3]);
            u[2] = pk2(a1[0], a1[1]); u[3] = pk2(a1[2], a1[3]);
            af[mi] = *reinterpret_cast<short8*>(&u);
        }
        #pragma unroll
        for (int ni = 0; ni < 4; ++ni)
            bfr[ni] = *reinterpret_cast<const short8*>(&Bs[wc * 64 + ni * 16 + lrow][rslotB]);

        #pragma unroll
        for (int mi = 0; mi < 4; ++mi)
            #pragma unroll
            for (int ni = 0; ni < 4; ++ni)
                acc[mi][ni] = __builtin_amdgcn_mfma_f32_16x16x32_bf16(
                    af[mi], bfr[ni], acc[mi][ni], 0, 0, 0);

        __syncthreads();   // protect LDS before next stage
    }

    #pragma unroll
    for (int mi = 0; mi < 4; ++mi)
        #pragma unroll
        for (int ni = 0; ni < 4; ++ni)
            #pragma unroll
            for (int r = 0; r < 4; ++r)
                Cb[(size_t)(m0 + wr * 64 + mi * 16 + lkg * 4 + r) * NC
                   + (n0 + wc * 64 + ni * 16 + lrow)] = f2bf(acc[mi][ni][r]);
}

// ---------------- GEMM2: bf16 A/B via gload_lds, BK=64 dbuf (R8 path) ----------------

#define TM 128
#define TN 128
#define TK 64

__global__ __launch_bounds__(256) void gemm2_bf16(
    const unsigned short* __restrict__ Ab, const unsigned short* __restrict__ Bt,
    unsigned short* __restrict__ Cb, int M, int K, int Nc)
{
    __shared__ unsigned short As[2][TM][TK];   // 2 x 16 KB
    __shared__ unsigned short Bs[2][TN][TK];   // 2 x 16 KB

    const int tid  = threadIdx.x;
    const int lane = tid & 63;
    const int wave = tid >> 6;
    const int wr = wave >> 1, wc = wave & 1;
    const int lrow = lane & 15;
    const int lkg  = lane >> 4;

    const int per = gridDim.x / NXCD;
    const int newlin = (blockIdx.x % NXCD) * per + blockIdx.x / NXCD;
    const int ncb = Nc / TN;
    const int m0 = (newlin / ncb) * TM;
    const int n0 = (newlin % ncb) * TN;

    int srow[4], sq[4];
    #pragma unroll
    for (int i = 0; i < 4; ++i) {
        int s = i * 256 + wave * 64 + lane;
        srow[i] = s >> 3;
        sq[i] = (s & 7) ^ ((s >> 3) & 7);
    }

    char* AsB = (char*)&As[0][0][0];
    char* BsB = (char*)&Bs[0][0][0];

    auto stageOp = [&](const unsigned short* G, int rc0, int kt, char* opBase, int buf) {
        const int k0 = kt * TK;
        #pragma unroll
        for (int i = 0; i < 4; ++i)
            gload16(G + (size_t)(rc0 + srow[i]) * K + k0 + sq[i] * 8,
                    opBase + buf * 16384 + (i * 256 + wave * 64) * 16);
    };

    f32x4 acc[4][4] = {};

    stageOp(Bt, n0, 0, BsB, 0);
    stageOp(Ab, m0, 0, AsB, 0);
    __syncthreads();

    const int nk = K / TK;
    for (int kt = 0; kt < nk; ++kt) {
        const int cur = kt & 1, nxt = cur ^ 1;

        if (kt + 1 < nk) {
            stageOp(Bt, n0, kt + 1, BsB, nxt);
            stageOp(Ab, m0, kt + 1, AsB, nxt);
        }

        #pragma unroll
        for (int ks = 0; ks < 2; ++ks) {
            short8 af[4], bfr[4];
            #pragma unroll
            for (int mi = 0; mi < 4; ++mi) {
                const int row = wr * 64 + mi * 16 + lrow;
                const int qp = (ks * 4 + lkg) ^ (lrow & 7);
                af[mi] = *reinterpret_cast<const short8*>(&As[cur][row][qp * 8]);
            }
            #pragma unroll
            for (int ni = 0; ni < 4; ++ni) {
                const int row = wc * 64 + ni * 16 + lrow;
                const int qp = (ks * 4 + lkg) ^ (lrow & 7);
                bfr[ni] = *reinterpret_cast<const short8*>(&Bs[cur][row][qp * 8]);
            }
            #pragma unroll
            for (int mi = 0; mi < 4; ++mi)
                #pragma unroll
                for (int ni = 0; ni < 4; ++ni)
                    acc[mi][ni] = __builtin_amdgcn_mfma_f32_16x16x32_bf16(
                        af[mi], bfr[ni], acc[mi][ni], 0, 0, 0);
        }

        __syncthreads();
    }

    #pragma unroll
    for (int mi = 0; mi < 4; ++mi)
        #pragma unroll
        for (int ni = 0; ni < 4; ++ni)
            #pragma unroll
            for (int r = 0; r < 4; ++r)
                Cb[(size_t)(m0 + wr * 64 + mi * 16 + lkg * 4 + r) * Nc
                   + (n0 + wc * 64 + ni * 16 + lrow)] = f2bf(acc[mi][ni][r]);
}

// ---------------- CSR gather-aggregate (bf16 X), fused epilogues ----------------
// LAYER1: acc = sum iso[src]*X[src]; out_bf = bf16(elu(acc*isi + b1) * iso[node])
// else:   acc = sum X[src];          out_f  = acc*isi + b2

template<int DIM, bool LAYER1>
__global__ __launch_bounds__(256) void aggregate(
    const int* __restrict__ row_start, const int* __restrict__ eidx,
    const unsigned short* __restrict__ Xb, const float* __restrict__ isi,
    const float* __restrict__ iso, const float* __restrict__ bias,
    unsigned short* __restrict__ out_bf, float* __restrict__ out_f)
{
    constexpr int F = DIM / 64;           // 8 (HID) or 4 (OUTD)
    using VecT = typename VecSel<F>::T;
    const int node = blockIdx.x * 4 + (threadIdx.x >> 6);
    const int lane = threadIdx.x & 63;

    const int beg = row_start[node];
    const int end = row_start[node + 1];
    const unsigned short* base = Xb + lane * F;

    float acc[F] = {};
    int e = beg;
    for (; e + 3 < end; e += 4) {
        int i0 = eidx[e], i1 = eidx[e + 1], i2 = eidx[e + 2], i3 = eidx[e + 3];
        float s0 = 1.f, s1 = 1.f, s2 = 1.f, s3 = 1.f;
        if (LAYER1) { s0 = iso[i0]; s1 = iso[i1]; s2 = iso[i2]; s3 = iso[i3]; }
        VecT v0 = *reinterpret_cast<const VecT*>(base + (size_t)i0 * DIM);
        VecT v1 = *reinterpret_cast<const VecT*>(base + (size_t)i1 * DIM);
        VecT v2 = *reinterpret_cast<const VecT*>(base + (size_t)i2 * DIM);
        VecT v3 = *reinterpret_cast<const VecT*>(base + (size_t)i3 * DIM);
        #pragma unroll
        for (int f = 0; f < F; ++f) {
            if (LAYER1) {
                acc[f] = fmaf(s0, bf2f(v0[f]), acc[f]);
                acc[f] = fmaf(s1, bf2f(v1[f]), acc[f]);
                acc[f] = fmaf(s2, bf2f(v2[f]), acc[f]);
                acc[f] = fmaf(s3, bf2f(v3[f]), acc[f]);
            } else {
                acc[f] += bf2f(v0[f]); acc[f] += bf2f(v1[f]);
                acc[f] += bf2f(v2[f]); acc[f] += bf2f(v3[f]);
            }
        }
    }
    for (; e < end; ++e) {
        int i0 = eidx[e];
        float s0 = LAYER1 ? iso[i0] : 1.f;
        VecT v0 = *reinterpret_cast<const VecT*>(base + (size_t)i0 * DIM);
        #pragma unroll
        for (int f = 0; f < F; ++f)
            acc[f] = LAYER1 ? fmaf(s0, bf2f(v0[f]), acc[f]) : acc[f] + bf2f(v0[f]);
    }

    const float si = isi[node];
    float bv[F];
    #pragma unroll
    for (int q = 0; q < F / 4; ++q)
        *reinterpret_cast<float4*>(&bv[q * 4]) =
            *reinterpret_cast<const float4*>(bias + lane * F + q * 4);

    if (LAYER1) {
        const float so = iso[node];
        short8 o;
        #pragma unroll
        for (int f = 0; f < F; ++f) {
            float v = acc[f] * si + bv[f];
            v = v > 0.f ? v : expm1f(v);
            o[f] = (short)f2bf(v * so);
        }
        *reinterpret_cast<short8*>(out_bf + (size_t)node * DIM + lane * F) = o;
    } else {
        #pragma unroll
        for (int q = 0; q < F / 4; ++q) {
            float4 v = make_float4(acc[q * 4 + 0] * si + bv[q * 4 + 0],
                                   acc[q * 4 + 1] * si + bv[q * 4 + 1],
                                   acc[q * 4 + 2] * si + bv[q * 4 + 2],
                                   acc[q * 4 + 3] * si + bv[q * 4 + 3]);
            *reinterpret_cast<float4*>(out_f + (size_t)node * DIM + lane * F + q * 4) = v;
        }
    }
}

// ---------------- launch ----------------

extern "C" void kernel_launch(void* const* d_in, const int* in_sizes, int n_in,
                              void* d_out, int out_size, void* d_ws, size_t ws_size,
                              hipStream_t stream) {
    const float* h  = (const float*)d_in[0];
    const float* W1 = (const float*)d_in[1];
    const float* b1 = (const float*)d_in[2];
    const float* W2 = (const float*)d_in[3];
    const float* b2 = (const float*)d_in[4];
    const int*   src = (const int*)d_in[5];
    const int*   dst = (const int*)d_in[6];

    const int N = in_sizes[0] / IN_DIM;   // 65536
    const int E = in_sizes[5];            // 524288
    float* out = (float*)d_out;

    // ---- workspace layout ----
    int* dego      = (int*)d_ws;                   // N
    int* degi      = dego + N;                     // N
    int* excl      = degi + N;                     // N
    int* partials  = excl + N;                     // 256
    int* row_start = partials + 256;               // N+1 (pad to N+64)
    int* cursor    = row_start + N + 64;           // N
    int* eidx      = cursor + N;                   // E
    float* iso     = (float*)(eidx + E);           // N
    float* isi     = iso + N;                      // N
    unsigned short* W1t = (unsigned short*)(isi + N);      // IN_DIM*HID
    unsigned short* W2t = W1t + (size_t)IN_DIM * HID;      // HID*OUTD
    unsigned short* X1b = W2t + (size_t)HID * OUTD;        // N*HID bf16 (67MB)
    unsigned short* X2b = X1b;                             // alias (X1 dead before gemm2 write)
    unsigned short* R2h = X1b + (size_t)N * HID;           // N*HID bf16 (67MB) — x1s

    hipMemsetAsync(dego, 0, sizeof(int) * (size_t)2 * N, stream);

    deg_kernel<<<(E + 255) / 256, 256, 0, stream>>>(src, dst, dego, degi, E);
    invsqrt_kernel<<<(N + 255) / 256, 256, 0, stream>>>(dego, degi, iso, isi, N);

    // CSR by dst
    scan_block<<<N / 256, 256, 0, stream>>>(degi, excl, partials);
    scan_partials<<<1, 256, 0, stream>>>(partials);
    scan_add<<<N / 256, 256, 0, stream>>>(excl, partials, degi, row_start, cursor, N);
    csr_fill<<<(E + 255) / 256, 256, 0, stream>>>(src, dst, cursor, eidx, E);

    // weights -> bf16 transposed (tiled, coalesced)
    {
        dim3 g1(HID / 32, IN_DIM / 32);
        transpose_cvt_tiled<<<g1, 256, 0, stream>>>(W1, W1t, IN_DIM, HID);
        dim3 g2(OUTD / 32, HID / 32);
        transpose_cvt_tiled<<<g2, 256, 0, stream>>>(W2, W2t, HID, OUTD);
    }

    // Layer 1: X1b = bf16(h @ W1) [A via DMA, occupancy-forced];
    //          aggregate applies iso[src] during gather
    gemm1_f32lds<<<(N / 128) * (HID / 128), 256, 0, stream>>>(h, W1t, X1b, N);
    aggregate<HID, true><<<N / 4, 256, 0, stream>>>(
        row_start, eidx, X1b, isi, iso, b1, R2h, nullptr);

    // Layer 2: X2b = bf16(R2h @ W2) ; out = agg(X2b)*isi + b2
    gemm2_bf16<<<(N / TM) * (OUTD / TN), 256, 0, stream>>>(
        R2h, W2t, X2b, N, HID, OUTD);
    aggregate<OUTD, false><<<N / 4, 256, 0, stream>>>(
        row_start, eidx, X2b, isi, iso, b2, nullptr, out);
}